// Round 10
// baseline (101.040 us; speedup 1.0000x reference)
//
#include <hip/hip_runtime.h>
#include <math.h>

#define BB 2
#define LL 1024
#define DD 512
#define HH 8
#define DHD 64
#define QQ 64
#define NCC 16

typedef __attribute__((ext_vector_type(8))) short s8b;   // 8 bf16 (4 VGPRs)
typedef __attribute__((ext_vector_type(4))) float f4;    // 4 fp32 acc

__device__ __forceinline__ void gld16(const void* g, void* l) {
    __builtin_amdgcn_global_load_lds(
        (const __attribute__((address_space(1))) unsigned int*)g,
        (__attribute__((address_space(3))) unsigned int*)l, 16, 0, 0);
}

__device__ __forceinline__ void bf16split(float f, unsigned short& h, unsigned short& l) {
    unsigned u  = __float_as_uint(f);
    unsigned hb = (u + 0x7FFFu + ((u >> 16) & 1u)) & 0xFFFF0000u;   // RTNE bf16
    float fh = __uint_as_float(hb);
    float fl = f - fh;
    unsigned ul = __float_as_uint(fl);
    unsigned lb = (ul + 0x7FFFu + ((ul >> 16) & 1u)) >> 16;
    h = (unsigned short)(hb >> 16);
    l = (unsigned short)lb;
}

__device__ __forceinline__ unsigned pk2(unsigned short a, unsigned short b) {
    return (unsigned)a | ((unsigned)b << 16);
}

// ---------------------------------------------------------------------------
// Kernel 0: split x / Wa / Wb / Wc into bf16 hi/lo arrays (unchanged).
// ---------------------------------------------------------------------------
__global__ __launch_bounds__(256) void convert_split(
    const float* __restrict__ x, const float* __restrict__ Wa,
    const float* __restrict__ Wb, const float* __restrict__ Wc,
    unsigned short* __restrict__ xh, unsigned short* __restrict__ xl,
    unsigned short* __restrict__ wh, unsigned short* __restrict__ wl)
{
    const int g = blockIdx.x * 256 + threadIdx.x;    // float4 index
    const float* src;
    unsigned short *dh, *dl;
    if (g < 262144) {
        const size_t off = (size_t)g * 4;
        src = x + off; dh = xh + off; dl = xl + off;
    } else {
        const size_t j = (size_t)(g - 262144) * 4;   // 0..786431
        const int wsel = (int)(j >> 18);             // 262144 elements each
        const size_t r = j & 262143;
        src = (wsel == 0 ? Wa : (wsel == 1 ? Wb : Wc)) + r;
        dh = wh + j; dl = wl + j;
    }
    const float4 v = *(const float4*)src;
    const float f[4] = {v.x, v.y, v.z, v.w};
    unsigned short h[4], l[4];
    #pragma unroll
    for (int i = 0; i < 4; ++i) bf16split(f[i], h[i], l[i]);
    *(uint2*)dh = make_uint2(pk2(h[0], h[1]), pk2(h[2], h[3]));
    *(uint2*)dl = make_uint2(pk2(l[0], l[1]), pk2(l[2], l[3]));
}

// ---------------------------------------------------------------------------
// Kernel 1: fused 3-weight MFMA GEMM, double-buffered (unchanged).
// ---------------------------------------------------------------------------
__global__ __launch_bounds__(512) void gemm3_fused(
    const unsigned short* __restrict__ xh, const unsigned short* __restrict__ xl,
    const unsigned short* __restrict__ wh, const unsigned short* __restrict__ wl,
    const float* __restrict__ ba, const float* __restrict__ bb, const float* __restrict__ bc,
    float* __restrict__ logA, float* __restrict__ Bf, float* __restrict__ Cf)
{
    __shared__ unsigned char lds[65536];

    const int bm = blockIdx.x >> 3;
    const int bn = blockIdx.x & 7;
    const int m0 = bm << 6, o0 = bn << 6;
    const int t = threadIdx.x, wv = t >> 6, ln = t & 63;
    const int l15 = ln & 15, l4 = ln >> 4;
    const int wr = (wv >> 2) << 5;      // 0 / 32
    const int wc = (wv & 3) << 4;       // 0 / 16 / 32 / 48

    const unsigned short* hp = (wv < 2) ? xh : wh + (size_t)((wv - 2) >> 1) * 262144;
    const unsigned short* lp = (wv < 2) ? xl : wl + (size_t)((wv - 2) >> 1) * 262144;
    const size_t grow = (size_t)(((wv < 2) ? m0 : o0) + ln) * DD;
    const unsigned short* sp = ((wv & 1) ? lp : hp) + grow;
    const int abase = wv * 4096;

    f4 acc[3][2] = {};

    auto STAGE = [&](int buf, int kt) {
        unsigned char* base = lds + buf * 32768 + abase;
        #pragma unroll
        for (int s = 0; s < 4; ++s)
            gld16(sp + kt + s * 8, base + s * 1024);
    };

    auto COMPUTE = [&](int buf) {
        const unsigned char* base = lds + buf * 32768;
        const int ka = l4 * 1024;
        const s8b ah0 = *(const s8b*)(base + 0*4096 + ka + (wr      + l15) * 16);
        const s8b ah1 = *(const s8b*)(base + 0*4096 + ka + (wr + 16 + l15) * 16);
        const s8b al0 = *(const s8b*)(base + 1*4096 + ka + (wr      + l15) * 16);
        const s8b al1 = *(const s8b*)(base + 1*4096 + ka + (wr + 16 + l15) * 16);
        #pragma unroll
        for (int s = 0; s < 3; ++s) {
            const s8b bh = *(const s8b*)(base + (2 + 2*s)*4096 + ka + (wc + l15) * 16);
            const s8b bl = *(const s8b*)(base + (3 + 2*s)*4096 + ka + (wc + l15) * 16);
            acc[s][0] = __builtin_amdgcn_mfma_f32_16x16x32_bf16(ah0, bh, acc[s][0], 0, 0, 0);
            acc[s][1] = __builtin_amdgcn_mfma_f32_16x16x32_bf16(ah1, bh, acc[s][1], 0, 0, 0);
            acc[s][0] = __builtin_amdgcn_mfma_f32_16x16x32_bf16(ah0, bl, acc[s][0], 0, 0, 0);
            acc[s][1] = __builtin_amdgcn_mfma_f32_16x16x32_bf16(ah1, bl, acc[s][1], 0, 0, 0);
            acc[s][0] = __builtin_amdgcn_mfma_f32_16x16x32_bf16(al0, bh, acc[s][0], 0, 0, 0);
            acc[s][1] = __builtin_amdgcn_mfma_f32_16x16x32_bf16(al1, bh, acc[s][1], 0, 0, 0);
        }
    };

    STAGE(0, 0);
    __syncthreads();
    int cur = 0;
    for (int it = 0; it < 16; ++it) {
        if (it < 15) STAGE(cur ^ 1, (it + 1) * 32);
        COMPUTE(cur);
        __syncthreads();
        cur ^= 1;
    }

    const int col = o0 + wc + l15;
    const float bva = ba[col], bvb = bb[col], bvc = bc[col];
    #pragma unroll
    for (int ms = 0; ms < 2; ++ms) {
        const int row0 = m0 + wr + ms * 16 + l4 * 4;
        #pragma unroll
        for (int r = 0; r < 4; ++r) {
            const size_t o = (size_t)(row0 + r) * DD + col;
            float va = acc[0][ms][r] + bva;
            logA[o] = fminf(va, 0.f) - log1pf(__expf(-fabsf(va)));
            Bf[o] = acc[1][ms][r] + bvb;
            Cf[o] = acc[2][ms][r] + bvc;
        }
    }
}

// ---------------------------------------------------------------------------
// Kernel 2a: per-chunk sums of logA (unchanged).
// ---------------------------------------------------------------------------
__global__ __launch_bounds__(256) void chunk_sums256(
    const float* __restrict__ logA, float* __restrict__ csum)
{
    __shared__ float part[4][DHD];
    const int blk = blockIdx.x;       // bh*16 + c
    const int bh = blk >> 4, c = blk & 15;
    const int b = bh >> 3, h = bh & 7;
    const int t = threadIdx.x;
    const int d = t & 63, w = t >> 6;
    const size_t base = (size_t)(b * LL + c * QQ + w * 16) * DD + h * DHD + d;
    float s = 0.f;
    #pragma unroll 4
    for (int i = 0; i < 16; ++i) s += logA[base + (size_t)i * DD];
    part[w][d] = s;
    __syncthreads();
    if (t < DHD)
        csum[(size_t)blk * DHD + t] = part[0][t] + part[1][t] + part[2][t] + part[3][t];
}

// ---------------------------------------------------------------------------
// Kernel 2b: scan (unchanged).
// ---------------------------------------------------------------------------
__global__ __launch_bounds__(256) void scan256(
    const float* __restrict__ logA, const float* __restrict__ Bf,
    const float* __restrict__ Cf, const float* __restrict__ csum,
    float* __restrict__ Sloc, float* __restrict__ qf, float* __restrict__ kf,
    float* __restrict__ coff)
{
    __shared__ float part[4][DHD];
    const int blk = blockIdx.x;
    const int bh = blk >> 4, c = blk & 15;
    const int b = bh >> 3, h = bh & 7;
    const int t = threadIdx.x;
    const int d = t & 63, w = t >> 6;

    const size_t gbase = (size_t)(b * LL + c * QQ + w * 16) * DD + h * DHD + d;
    float ps = 0.f;
    #pragma unroll 4
    for (int i = 0; i < 16; ++i) ps += logA[gbase + (size_t)i * DD];
    part[w][d] = ps;
    __syncthreads();

    const size_t cs0 = ((size_t)bh << 4) * DHD + d;
    float off = 0.f;
    for (int cc = 0; cc < c; ++cc) off += csum[cs0 + (size_t)cc * DHD];
    const float tot = part[0][d] + part[1][d] + part[2][d] + part[3][d];
    if (t < DHD) {
        coff[((size_t)bh * 17 + c) * DHD + t] = off;
        if (c == NCC - 1) coff[((size_t)bh * 17 + 16) * DHD + t] = off + tot;
    }

    float run = 0.f;
    for (int ww = 0; ww < 4; ++ww) if (ww < w) run += part[ww][d];

    const size_t hbase = ((size_t)bh * LL + c * QQ + w * 16) * DHD + d;
    #pragma unroll 4
    for (int i = 0; i < 16; ++i) {
        const size_t gi = gbase + (size_t)i * DD;
        const float la = logA[gi];
        const float cv = Cf[gi];
        const float bv = Bf[gi];
        qf[hbase + (size_t)i * DHD] = cv * __expf(run);       // exp(Sm1 - Eprev)
        run += la;
        Sloc[hbase + (size_t)i * DHD] = run;
        kf[hbase + (size_t)i * DHD] = bv * __expf(tot - run); // exp(E - S)
    }
}

// ---------------------------------------------------------------------------
// Kernel 3: band v4 (R8 body, 4-tile granularity). Block = (bh, m, q4);
//  owns n in [4q4, 4q4+4). Zeros up front; diag skipped; offdiag with qf
//  staged once + kf double-buffer. Grid 1024 -> 3 blocks/CU (48 KB LDS).
// ---------------------------------------------------------------------------
__global__ __launch_bounds__(256) void band_row(
    const float* __restrict__ qf, const float* __restrict__ kf,
    const float* __restrict__ coff, float* __restrict__ out)
{
    __shared__ unsigned char lds[49152];
    unsigned char* const l_qh = lds;
    unsigned char* const l_ql = lds + 8192;
    // k buffers: base 16384 + buf*16384, kh at +0, kl at +8192

    const int q4 = blockIdx.x & 3;
    const int m  = (blockIdx.x >> 2) & 15;
    const int bh = blockIdx.x >> 6;
    const int n0 = q4 << 2;

    const int t  = threadIdx.x;
    const int wv = t >> 6;
    const int ln = t & 63;
    const int l15 = ln & 15;
    const int l4  = ln >> 4;
    const int wr = (wv >> 1) << 5;           // k-side half (A operand)
    const int wc = (wv & 1) << 5;            // q-side half (B operand)

    const int srow = t >> 2;                 // 0..63
    const int skc  = (t & 3) << 4;           // 0/16/32/48
    const int slot0 = skc >> 3;

    const size_t cb = (size_t)bh * 17 * DHD;
    const size_t outbase = ((size_t)bh * LL + (size_t)m * QQ) * LL;

    // ---- zero tiles (n > m within range), no LDS involved ----
    for (int n = (m >= n0 ? m + 1 : n0); n < n0 + 4; ++n) {
        const size_t ob = outbase + (size_t)srow * LL + (size_t)n * QQ + skc;
        const float4 z = make_float4(0.f, 0.f, 0.f, 0.f);
        *(float4*)&out[ob + 0]  = z;
        *(float4*)&out[ob + 4]  = z;
        *(float4*)&out[ob + 8]  = z;
        *(float4*)&out[ob + 12] = z;
    }

    const int ne = (m < n0 + 4) ? m : (n0 + 4);   // offdiag n in [n0, ne)
    if (n0 >= ne) return;

    // ---- coff[m] slice for this thread's 16 k-columns ----
    float cm[16];
    #pragma unroll
    for (int g = 0; g < 4; ++g) {
        const float4 a = *(const float4*)&coff[cb + (size_t)m * DHD + skc + g * 4];
        cm[g*4+0]=a.x; cm[g*4+1]=a.y; cm[g*4+2]=a.z; cm[g*4+3]=a.w;
    }

    // ---- stage qf_m once (hi/lo split) ----
    {
        const size_t qb = ((size_t)bh * LL + (size_t)m * QQ + srow) * DHD + skc;
        float v[16];
        #pragma unroll
        for (int g = 0; g < 4; ++g) {
            const float4 x4 = *(const float4*)&qf[qb + g * 4];
            v[g*4+0]=x4.x; v[g*4+1]=x4.y; v[g*4+2]=x4.z; v[g*4+3]=x4.w;
        }
        unsigned short h[16], l[16];
        #pragma unroll
        for (int i = 0; i < 16; ++i) bf16split(v[i], h[i], l[i]);
        *(uint4*)(l_qh + slot0*1024 + srow*16) =
            make_uint4(pk2(h[0],h[1]), pk2(h[2],h[3]), pk2(h[4],h[5]), pk2(h[6],h[7]));
        *(uint4*)(l_qh + (slot0+1)*1024 + srow*16) =
            make_uint4(pk2(h[8],h[9]), pk2(h[10],h[11]), pk2(h[12],h[13]), pk2(h[14],h[15]));
        *(uint4*)(l_ql + slot0*1024 + srow*16) =
            make_uint4(pk2(l[0],l[1]), pk2(l[2],l[3]), pk2(l[4],l[5]), pk2(l[6],l[7]));
        *(uint4*)(l_ql + (slot0+1)*1024 + srow*16) =
            make_uint4(pk2(l[8],l[9]), pk2(l[10],l[11]), pk2(l[12],l[13]), pk2(l[14],l[15]));
    }

    // ---- kf staging helper: exp-scale, split, write to LDS buf ----
    auto STAGE_K = [&](int buf, int n) {
        unsigned char* const kh_b = lds + 16384 + buf * 16384;
        unsigned char* const kl_b = kh_b + 8192;
        float dv[16];
        #pragma unroll
        for (int g = 0; g < 4; ++g) {
            const float4 c4 = *(const float4*)&coff[cb + (size_t)(n + 1) * DHD + skc + g * 4];
            dv[g*4+0] = __expf(cm[g*4+0] - c4.x);
            dv[g*4+1] = __expf(cm[g*4+1] - c4.y);
            dv[g*4+2] = __expf(cm[g*4+2] - c4.z);
            dv[g*4+3] = __expf(cm[g*4+3] - c4.w);
        }
        const size_t kb = ((size_t)bh * LL + (size_t)n * QQ + srow) * DHD + skc;
        float v[16];
        #pragma unroll
        for (int g = 0; g < 4; ++g) {
            const float4 x4 = *(const float4*)&kf[kb + g * 4];
            v[g*4+0]=x4.x*dv[g*4+0]; v[g*4+1]=x4.y*dv[g*4+1];
            v[g*4+2]=x4.z*dv[g*4+2]; v[g*4+3]=x4.w*dv[g*4+3];
        }
        unsigned short h[16], l[16];
        #pragma unroll
        for (int i = 0; i < 16; ++i) bf16split(v[i], h[i], l[i]);
        *(uint4*)(kh_b + slot0*1024 + srow*16) =
            make_uint4(pk2(h[0],h[1]), pk2(h[2],h[3]), pk2(h[4],h[5]), pk2(h[6],h[7]));
        *(uint4*)(kh_b + (slot0+1)*1024 + srow*16) =
            make_uint4(pk2(h[8],h[9]), pk2(h[10],h[11]), pk2(h[12],h[13]), pk2(h[14],h[15]));
        *(uint4*)(kl_b + slot0*1024 + srow*16) =
            make_uint4(pk2(l[0],l[1]), pk2(l[2],l[3]), pk2(l[4],l[5]), pk2(l[6],l[7]));
        *(uint4*)(kl_b + (slot0+1)*1024 + srow*16) =
            make_uint4(pk2(l[8],l[9]), pk2(l[10],l[11]), pk2(l[12],l[13]), pk2(l[14],l[15]));
    };

    STAGE_K(0, n0);
    __syncthreads();

    int cur = 0;
    for (int n = n0; n < ne; ++n) {
        if (n + 1 < ne) STAGE_K(cur ^ 1, n + 1);   // prefetch next tile's kf

        const unsigned char* const kh_b = lds + 16384 + cur * 16384;
        const unsigned char* const kl_b = kh_b + 8192;

        f4 acc[2][2] = {};   // [ms: k-half][ns: q-half]
        #pragma unroll
        for (int ks = 0; ks < 2; ++ks) {
            const int ka = (ks * 4 + l4) * 1024;
            const s8b kh0 = *(const s8b*)(kh_b + ka + (wr      + l15) * 16);
            const s8b kh1 = *(const s8b*)(kh_b + ka + (wr + 16 + l15) * 16);
            const s8b kl0 = *(const s8b*)(kl_b + ka + (wr      + l15) * 16);
            const s8b kl1 = *(const s8b*)(kl_b + ka + (wr + 16 + l15) * 16);
            const s8b qh0 = *(const s8b*)(l_qh + ka + (wc      + l15) * 16);
            const s8b qh1 = *(const s8b*)(l_qh + ka + (wc + 16 + l15) * 16);
            const s8b ql0 = *(const s8b*)(l_ql + ka + (wc      + l15) * 16);
            const s8b ql1 = *(const s8b*)(l_ql + ka + (wc + 16 + l15) * 16);

            acc[0][0] = __builtin_amdgcn_mfma_f32_16x16x32_bf16(kh0, qh0, acc[0][0], 0, 0, 0);
            acc[0][1] = __builtin_amdgcn_mfma_f32_16x16x32_bf16(kh0, qh1, acc[0][1], 0, 0, 0);
            acc[1][0] = __builtin_amdgcn_mfma_f32_16x16x32_bf16(kh1, qh0, acc[1][0], 0, 0, 0);
            acc[1][1] = __builtin_amdgcn_mfma_f32_16x16x32_bf16(kh1, qh1, acc[1][1], 0, 0, 0);
            acc[0][0] = __builtin_amdgcn_mfma_f32_16x16x32_bf16(kh0, ql0, acc[0][0], 0, 0, 0);
            acc[0][1] = __builtin_amdgcn_mfma_f32_16x16x32_bf16(kh0, ql1, acc[0][1], 0, 0, 0);
            acc[1][0] = __builtin_amdgcn_mfma_f32_16x16x32_bf16(kh1, ql0, acc[1][0], 0, 0, 0);
            acc[1][1] = __builtin_amdgcn_mfma_f32_16x16x32_bf16(kh1, ql1, acc[1][1], 0, 0, 0);
            acc[0][0] = __builtin_amdgcn_mfma_f32_16x16x32_bf16(kl0, qh0, acc[0][0], 0, 0, 0);
            acc[0][1] = __builtin_amdgcn_mfma_f32_16x16x32_bf16(kl0, qh1, acc[0][1], 0, 0, 0);
            acc[1][0] = __builtin_amdgcn_mfma_f32_16x16x32_bf16(kl1, qh0, acc[1][0], 0, 0, 0);
            acc[1][1] = __builtin_amdgcn_mfma_f32_16x16x32_bf16(kl1, qh1, acc[1][1], 0, 0, 0);
        }

        // lane holds T[q][k0..k0+3]: q = wc+ns*16+l15, k0 = wr+ms*16+l4*4
        #pragma unroll
        for (int ms = 0; ms < 2; ++ms) {
            #pragma unroll
            for (int ns = 0; ns < 2; ++ns) {
                const int q  = wc + ns * 16 + l15;
                const int k0 = wr + ms * 16 + l4 * 4;
                *(float4*)&out[outbase + (size_t)q * LL + (size_t)n * QQ + k0] =
                    make_float4(acc[ms][ns][0], acc[ms][ns][1], acc[ms][ns][2], acc[ms][ns][3]);
            }
        }
        __syncthreads();   // staged n+1 visible; buf cur free for overwrite
        cur ^= 1;
    }
}

// ---------------------------------------------------------------------------
// Kernel 4: diagonal tiles (unchanged R8 version, own kernel).
// ---------------------------------------------------------------------------
__global__ __launch_bounds__(256) void diag_kernel(
    const float* __restrict__ Sloc, const float* __restrict__ Bf,
    const float* __restrict__ Cf, float* __restrict__ out)
{
    __shared__ float smA[DHD][65];
    __shared__ float smB[DHD][65];
    __shared__ float smC[DHD][65];

    const int blk = blockIdx.x;      // bh*16 + m
    const int bh = blk >> 4, m = blk & 15;
    const int b = bh >> 3, h = bh & 7;
    const int t = threadIdx.x;
    const int q0 = ((t >> 4) & 15) << 2;
    const int k0 = (t & 15) << 2;
    const int r  = t >> 4;
    const int dg = (t & 15) << 2;

    const size_t ab = (size_t)(b * LL + m * QQ) * DD + h * DHD;
    const size_t sb = ((size_t)bh * LL + (size_t)m * QQ) * DHD;
    #pragma unroll
    for (int rr = 0; rr < 64; rr += 16) {
        const int row = r + rr;
        float4 cv = *(const float4*)&Cf[ab + (size_t)row * DD + dg];
        smA[dg+0][row] = cv.x; smA[dg+1][row] = cv.y; smA[dg+2][row] = cv.z; smA[dg+3][row] = cv.w;
        float4 bv = *(const float4*)&Bf[ab + (size_t)row * DD + dg];
        smB[dg+0][row] = bv.x; smB[dg+1][row] = bv.y; smB[dg+2][row] = bv.z; smB[dg+3][row] = bv.w;
        float4 sv = *(const float4*)&Sloc[sb + (size_t)row * DHD + dg];
        smC[dg+0][row] = sv.x; smC[dg+1][row] = sv.y; smC[dg+2][row] = sv.z; smC[dg+3][row] = sv.w;
    }
    __syncthreads();

    float acc[4][4] = {};
    if (q0 + 3 >= k0) {
        #pragma unroll 2
        for (int d = 0; d < DHD; ++d) {
            const float4 cq = *(const float4*)&smA[d][q0];
            const float4 bk = *(const float4*)&smB[d][k0];
            const float4 sk = *(const float4*)&smC[d][k0];
            const float cqa[4] = {cq.x, cq.y, cq.z, cq.w};
            const float bka[4] = {bk.x, bk.y, bk.z, bk.w};
            const float ska[4] = {sk.x, sk.y, sk.z, sk.w};
            float s1a[4];
            #pragma unroll
            for (int i = 0; i < 4; ++i) {
                const int qi = q0 + i;
                s1a[i] = (qi == 0) ? 0.f : smC[d][qi - 1];
            }
            #pragma unroll
            for (int i = 0; i < 4; ++i) {
                #pragma unroll
                for (int j = 0; j < 4; ++j) {
                    const int qi = q0 + i, kj = k0 + j;
                    const float wgt = (qi > kj) ? __expf(s1a[i] - ska[j])
                                                : ((qi == kj) ? 1.f : 0.f);
                    acc[i][j] += cqa[i] * wgt * bka[j];
                }
            }
        }
    }
    const size_t outrow0 = ((size_t)bh * LL + (size_t)m * QQ) * LL + (size_t)m * QQ;
    #pragma unroll
    for (int i = 0; i < 4; ++i)
        *(float4*)&out[outrow0 + (size_t)(q0 + i) * LL + k0] =
            make_float4(acc[i][0], acc[i][1], acc[i][2], acc[i][3]);
}

// ---------------------------------------------------------------------------
extern "C" void kernel_launch(void* const* d_in, const int* in_sizes, int n_in,
                              void* d_out, int out_size, void* d_ws, size_t ws_size,
                              hipStream_t stream) {
    const float* x  = (const float*)d_in[0];
    const float* Wa = (const float*)d_in[1];
    const float* ba = (const float*)d_in[2];
    const float* Wb = (const float*)d_in[3];
    const float* bb = (const float*)d_in[4];
    const float* Wc = (const float*)d_in[5];
    const float* bc = (const float*)d_in[6];
    float* out = (float*)d_out;
    float* ws  = (float*)d_ws;

    const size_t NBLD = (size_t)BB * LL * DD;   // 1,048,576 floats
    float* logA = ws;
    float* Bf   = ws + 1 * NBLD;
    float* Cf   = ws + 2 * NBLD;
    float* Sl   = ws + 3 * NBLD;
    float* qf   = ws + 4 * NBLD;
    float* kf   = ws + 5 * NBLD;
    float* coff = ws + 6 * NBLD;                        // 16*17*64 floats
    float* csum = coff + (size_t)BB * HH * 17 * DHD;    // 256*64 floats

    unsigned short* xh  = (unsigned short*)(ws + 3 * NBLD);
    unsigned short* xl  = xh + 1048576;
    unsigned short* whp = xl + 1048576;    // 3 x 262144
    unsigned short* wlp = whp + 786432;

    convert_split<<<1792, 256, 0, stream>>>(x, Wa, Wb, Wc, xh, xl, whp, wlp);
    gemm3_fused<<<256, 512, 0, stream>>>(xh, xl, whp, wlp, ba, bb, bc, logA, Bf, Cf);
    chunk_sums256<<<BB * HH * NCC, 256, 0, stream>>>(logA, csum);
    scan256<<<BB * HH * NCC, 256, 0, stream>>>(logA, Bf, Cf, csum, Sl, qf, kf, coff);
    band_row<<<BB * HH * NCC * 4, 256, 0, stream>>>(qf, kf, coff, out);
    diag_kernel<<<BB * HH * NCC, 256, 0, stream>>>(Sl, Bf, Cf, out);
}

// Round 11
// 93.215 us; speedup vs baseline: 1.0839x; 1.0839x over previous
//
#include <hip/hip_runtime.h>
#include <math.h>

#define BB 2
#define LL 1024
#define DD 512
#define HH 8
#define DHD 64
#define QQ 64
#define NCC 16

typedef __attribute__((ext_vector_type(8))) short s8b;   // 8 bf16 (4 VGPRs)
typedef __attribute__((ext_vector_type(4))) float f4;    // 4 fp32 acc

__device__ __forceinline__ void gld16(const void* g, void* l) {
    __builtin_amdgcn_global_load_lds(
        (const __attribute__((address_space(1))) unsigned int*)g,
        (__attribute__((address_space(3))) unsigned int*)l, 16, 0, 0);
}

__device__ __forceinline__ void bf16split(float f, unsigned short& h, unsigned short& l) {
    unsigned u  = __float_as_uint(f);
    unsigned hb = (u + 0x7FFFu + ((u >> 16) & 1u)) & 0xFFFF0000u;   // RTNE bf16
    float fh = __uint_as_float(hb);
    float fl = f - fh;
    unsigned ul = __float_as_uint(fl);
    unsigned lb = (ul + 0x7FFFu + ((ul >> 16) & 1u)) >> 16;
    h = (unsigned short)(hb >> 16);
    l = (unsigned short)lb;
}

__device__ __forceinline__ unsigned pk2(unsigned short a, unsigned short b) {
    return (unsigned)a | ((unsigned)b << 16);
}

// ---------------------------------------------------------------------------
// Kernel 0: split x / Wa / Wb / Wc into bf16 hi/lo arrays (unchanged).
// ---------------------------------------------------------------------------
__global__ __launch_bounds__(256) void convert_split(
    const float* __restrict__ x, const float* __restrict__ Wa,
    const float* __restrict__ Wb, const float* __restrict__ Wc,
    unsigned short* __restrict__ xh, unsigned short* __restrict__ xl,
    unsigned short* __restrict__ wh, unsigned short* __restrict__ wl)
{
    const int g = blockIdx.x * 256 + threadIdx.x;    // float4 index
    const float* src;
    unsigned short *dh, *dl;
    if (g < 262144) {
        const size_t off = (size_t)g * 4;
        src = x + off; dh = xh + off; dl = xl + off;
    } else {
        const size_t j = (size_t)(g - 262144) * 4;   // 0..786431
        const int wsel = (int)(j >> 18);             // 262144 elements each
        const size_t r = j & 262143;
        src = (wsel == 0 ? Wa : (wsel == 1 ? Wb : Wc)) + r;
        dh = wh + j; dl = wl + j;
    }
    const float4 v = *(const float4*)src;
    const float f[4] = {v.x, v.y, v.z, v.w};
    unsigned short h[4], l[4];
    #pragma unroll
    for (int i = 0; i < 4; ++i) bf16split(f[i], h[i], l[i]);
    *(uint2*)dh = make_uint2(pk2(h[0], h[1]), pk2(h[2], h[3]));
    *(uint2*)dl = make_uint2(pk2(l[0], l[1]), pk2(l[2], l[3]));
}

// ---------------------------------------------------------------------------
// Kernel 1: fused 3-weight MFMA GEMM, double-buffered. NEW: epilogue also
// reduces the logsigmoid tile column-wise -> csum[(b*8+h)*16+c][d], since
// block (bm,bn) computes exactly chunk (b=bm>>4, c=bm&15, h=bn)'s logA tile.
// ---------------------------------------------------------------------------
__global__ __launch_bounds__(512) void gemm3_fused(
    const unsigned short* __restrict__ xh, const unsigned short* __restrict__ xl,
    const unsigned short* __restrict__ wh, const unsigned short* __restrict__ wl,
    const float* __restrict__ ba, const float* __restrict__ bb, const float* __restrict__ bc,
    float* __restrict__ logA, float* __restrict__ Bf, float* __restrict__ Cf,
    float* __restrict__ csum)
{
    __shared__ unsigned char lds[65536];
    __shared__ float csv[64];

    const int bm = blockIdx.x >> 3;
    const int bn = blockIdx.x & 7;
    const int m0 = bm << 6, o0 = bn << 6;
    const int t = threadIdx.x, wv = t >> 6, ln = t & 63;
    const int l15 = ln & 15, l4 = ln >> 4;
    const int wr = (wv >> 2) << 5;      // 0 / 32
    const int wc = (wv & 3) << 4;       // 0 / 16 / 32 / 48

    const unsigned short* hp = (wv < 2) ? xh : wh + (size_t)((wv - 2) >> 1) * 262144;
    const unsigned short* lp = (wv < 2) ? xl : wl + (size_t)((wv - 2) >> 1) * 262144;
    const size_t grow = (size_t)(((wv < 2) ? m0 : o0) + ln) * DD;
    const unsigned short* sp = ((wv & 1) ? lp : hp) + grow;
    const int abase = wv * 4096;

    f4 acc[3][2] = {};

    auto STAGE = [&](int buf, int kt) {
        unsigned char* base = lds + buf * 32768 + abase;
        #pragma unroll
        for (int s = 0; s < 4; ++s)
            gld16(sp + kt + s * 8, base + s * 1024);
    };

    auto COMPUTE = [&](int buf) {
        const unsigned char* base = lds + buf * 32768;
        const int ka = l4 * 1024;
        const s8b ah0 = *(const s8b*)(base + 0*4096 + ka + (wr      + l15) * 16);
        const s8b ah1 = *(const s8b*)(base + 0*4096 + ka + (wr + 16 + l15) * 16);
        const s8b al0 = *(const s8b*)(base + 1*4096 + ka + (wr      + l15) * 16);
        const s8b al1 = *(const s8b*)(base + 1*4096 + ka + (wr + 16 + l15) * 16);
        #pragma unroll
        for (int s = 0; s < 3; ++s) {
            const s8b bh = *(const s8b*)(base + (2 + 2*s)*4096 + ka + (wc + l15) * 16);
            const s8b bl = *(const s8b*)(base + (3 + 2*s)*4096 + ka + (wc + l15) * 16);
            acc[s][0] = __builtin_amdgcn_mfma_f32_16x16x32_bf16(ah0, bh, acc[s][0], 0, 0, 0);
            acc[s][1] = __builtin_amdgcn_mfma_f32_16x16x32_bf16(ah1, bh, acc[s][1], 0, 0, 0);
            acc[s][0] = __builtin_amdgcn_mfma_f32_16x16x32_bf16(ah0, bl, acc[s][0], 0, 0, 0);
            acc[s][1] = __builtin_amdgcn_mfma_f32_16x16x32_bf16(ah1, bl, acc[s][1], 0, 0, 0);
            acc[s][0] = __builtin_amdgcn_mfma_f32_16x16x32_bf16(al0, bh, acc[s][0], 0, 0, 0);
            acc[s][1] = __builtin_amdgcn_mfma_f32_16x16x32_bf16(al1, bh, acc[s][1], 0, 0, 0);
        }
    };

    STAGE(0, 0);
    __syncthreads();
    int cur = 0;
    for (int it = 0; it < 16; ++it) {
        if (it < 15) STAGE(cur ^ 1, (it + 1) * 32);
        COMPUTE(cur);
        __syncthreads();
        cur ^= 1;
    }

    const int col = o0 + wc + l15;
    const float bva = ba[col], bvb = bb[col], bvc = bc[col];
    float asum = 0.f;
    #pragma unroll
    for (int ms = 0; ms < 2; ++ms) {
        const int row0 = m0 + wr + ms * 16 + l4 * 4;
        #pragma unroll
        for (int r = 0; r < 4; ++r) {
            const size_t o = (size_t)(row0 + r) * DD + col;
            float va = acc[0][ms][r] + bva;
            va = fminf(va, 0.f) - log1pf(__expf(-fabsf(va)));   // logsigmoid
            logA[o] = va;
            asum += va;
            Bf[o] = acc[1][ms][r] + bvb;
            Cf[o] = acc[2][ms][r] + bvc;
        }
    }

    // column-sum of the logsigmoid tile -> csum[chunk][d]
    // lanes with same col within a wave: l4 in 0..3 (lane bits 4,5)
    asum += __shfl_xor(asum, 16);
    asum += __shfl_xor(asum, 32);
    // cross-wave pair (wv, wv+4) share wc; combine via LDS
    if (wv < 4 && l4 == 0) csv[wc + l15] = asum;
    __syncthreads();
    if (wv >= 4 && l4 == 0) {
        const int blkc = (((bm >> 4) * 8 + bn) << 4) + (bm & 15);   // (b*8+h)*16+c
        csum[(size_t)blkc * DHD + wc + l15] = csv[wc + l15] + asum;
    }
}

// ---------------------------------------------------------------------------
// Kernel 2: scan + fused diag tile. Block (bh, c) = 256 blocks, 256 thr.
// Phase A: per-chunk partial sums; coff. Phase B: rescan writing qf/kf and
// stashing Sloc/B/C into LDS. Phase C: diag tile (verbatim R8 compute) from
// the LDS stash -> out[(bh, c, c)]. Sloc never goes to global.
// ---------------------------------------------------------------------------
__global__ __launch_bounds__(256) void scan_diag(
    const float* __restrict__ logA, const float* __restrict__ Bf,
    const float* __restrict__ Cf, const float* __restrict__ csum,
    float* __restrict__ qf, float* __restrict__ kf,
    float* __restrict__ coff, float* __restrict__ out)
{
    __shared__ float part[4][DHD];
    __shared__ float smA[DHD][65];   // Cf stash [d][row]
    __shared__ float smB[DHD][65];   // Bf stash
    __shared__ float smC[DHD][65];   // Sloc stash

    const int blk = blockIdx.x;
    const int bh = blk >> 4, c = blk & 15;
    const int b = bh >> 3, h = bh & 7;
    const int t = threadIdx.x;
    const int d = t & 63, w = t >> 6;

    const size_t gbase = (size_t)(b * LL + c * QQ + w * 16) * DD + h * DHD + d;
    float ps = 0.f;
    #pragma unroll 4
    for (int i = 0; i < 16; ++i) ps += logA[gbase + (size_t)i * DD];
    part[w][d] = ps;
    __syncthreads();

    const size_t cs0 = ((size_t)bh << 4) * DHD + d;
    float off = 0.f;
    for (int cc = 0; cc < c; ++cc) off += csum[cs0 + (size_t)cc * DHD];
    const float tot = part[0][d] + part[1][d] + part[2][d] + part[3][d];
    if (t < DHD) {
        coff[((size_t)bh * 17 + c) * DHD + t] = off;
        if (c == NCC - 1) coff[((size_t)bh * 17 + 16) * DHD + t] = off + tot;
    }

    float run = 0.f;
    for (int ww = 0; ww < 4; ++ww) if (ww < w) run += part[ww][d];

    const size_t hbase = ((size_t)bh * LL + c * QQ + w * 16) * DHD + d;
    #pragma unroll 4
    for (int i = 0; i < 16; ++i) {
        const size_t gi = gbase + (size_t)i * DD;
        const float la = logA[gi];
        const float cv = Cf[gi];
        const float bv = Bf[gi];
        qf[hbase + (size_t)i * DHD] = cv * __expf(run);       // exp(Sm1 - Eprev)
        run += la;
        const int rloc = w * 16 + i;
        smC[d][rloc] = run;       // Sloc
        smA[d][rloc] = cv;        // C
        smB[d][rloc] = bv;        // B
        kf[hbase + (size_t)i * DHD] = bv * __expf(tot - run); // exp(E - S)
    }
    __syncthreads();

    // ---- diag tile compute (R8 body, fed from LDS stash) ----
    const int q0 = ((t >> 4) & 15) << 2;
    const int k0 = (t & 15) << 2;

    float acc[4][4] = {};
    if (q0 + 3 >= k0) {
        #pragma unroll 2
        for (int dd = 0; dd < DHD; ++dd) {
            const float4 cq = *(const float4*)&smA[dd][q0];
            const float4 bk = *(const float4*)&smB[dd][k0];
            const float4 sk = *(const float4*)&smC[dd][k0];
            const float cqa[4] = {cq.x, cq.y, cq.z, cq.w};
            const float bka[4] = {bk.x, bk.y, bk.z, bk.w};
            const float ska[4] = {sk.x, sk.y, sk.z, sk.w};
            float s1a[4];
            #pragma unroll
            for (int i = 0; i < 4; ++i) {
                const int qi = q0 + i;
                s1a[i] = (qi == 0) ? 0.f : smC[dd][qi - 1];
            }
            #pragma unroll
            for (int i = 0; i < 4; ++i) {
                #pragma unroll
                for (int j = 0; j < 4; ++j) {
                    const int qi = q0 + i, kj = k0 + j;
                    const float wgt = (qi > kj) ? __expf(s1a[i] - ska[j])
                                                : ((qi == kj) ? 1.f : 0.f);
                    acc[i][j] += cqa[i] * wgt * bka[j];
                }
            }
        }
    }
    const size_t outrow0 = ((size_t)bh * LL + (size_t)c * QQ) * LL + (size_t)c * QQ;
    #pragma unroll
    for (int i = 0; i < 4; ++i)
        *(float4*)&out[outrow0 + (size_t)(q0 + i) * LL + k0] =
            make_float4(acc[i][0], acc[i][1], acc[i][2], acc[i][3]);
}

// ---------------------------------------------------------------------------
// Kernel 3: band v3 (R8 exact). Block = (bh, m, half); n in [8*half, 8*half+8).
//  Zeros up front; diag skipped; offdiag with qf staged once + kf dbuf.
//  LDS 48 KB -> up to 3 blocks/CU at grid 512.
// ---------------------------------------------------------------------------
__global__ __launch_bounds__(256) void band_row(
    const float* __restrict__ qf, const float* __restrict__ kf,
    const float* __restrict__ coff, float* __restrict__ out)
{
    __shared__ unsigned char lds[49152];
    unsigned char* const l_qh = lds;
    unsigned char* const l_ql = lds + 8192;
    // k buffers: base 16384 + buf*16384, kh at +0, kl at +8192

    const int half = blockIdx.x & 1;
    const int m    = (blockIdx.x >> 1) & 15;
    const int bh   = blockIdx.x >> 5;
    const int n0   = half << 3;

    const int t  = threadIdx.x;
    const int wv = t >> 6;
    const int ln = t & 63;
    const int l15 = ln & 15;
    const int l4  = ln >> 4;
    const int wr = (wv >> 1) << 5;           // k-side half (A operand)
    const int wc = (wv & 1) << 5;            // q-side half (B operand)

    const int srow = t >> 2;                 // 0..63
    const int skc  = (t & 3) << 4;           // 0/16/32/48
    const int slot0 = skc >> 3;

    const size_t cb = (size_t)bh * 17 * DHD;
    const size_t outbase = ((size_t)bh * LL + (size_t)m * QQ) * LL;

    // ---- zero tiles (n > m within range), no LDS involved ----
    for (int n = (m >= n0 ? m + 1 : n0); n < n0 + 8; ++n) {
        const size_t ob = outbase + (size_t)srow * LL + (size_t)n * QQ + skc;
        const float4 z = make_float4(0.f, 0.f, 0.f, 0.f);
        *(float4*)&out[ob + 0]  = z;
        *(float4*)&out[ob + 4]  = z;
        *(float4*)&out[ob + 8]  = z;
        *(float4*)&out[ob + 12] = z;
    }

    const int ne = (m < n0 + 8) ? m : (n0 + 8);   // offdiag n in [n0, ne)
    if (n0 >= ne) return;

    // ---- coff[m] slice for this thread's 16 k-columns ----
    float cm[16];
    #pragma unroll
    for (int g = 0; g < 4; ++g) {
        const float4 a = *(const float4*)&coff[cb + (size_t)m * DHD + skc + g * 4];
        cm[g*4+0]=a.x; cm[g*4+1]=a.y; cm[g*4+2]=a.z; cm[g*4+3]=a.w;
    }

    // ---- stage qf_m once (hi/lo split) ----
    {
        const size_t qb = ((size_t)bh * LL + (size_t)m * QQ + srow) * DHD + skc;
        float v[16];
        #pragma unroll
        for (int g = 0; g < 4; ++g) {
            const float4 x4 = *(const float4*)&qf[qb + g * 4];
            v[g*4+0]=x4.x; v[g*4+1]=x4.y; v[g*4+2]=x4.z; v[g*4+3]=x4.w;
        }
        unsigned short h[16], l[16];
        #pragma unroll
        for (int i = 0; i < 16; ++i) bf16split(v[i], h[i], l[i]);
        *(uint4*)(l_qh + slot0*1024 + srow*16) =
            make_uint4(pk2(h[0],h[1]), pk2(h[2],h[3]), pk2(h[4],h[5]), pk2(h[6],h[7]));
        *(uint4*)(l_qh + (slot0+1)*1024 + srow*16) =
            make_uint4(pk2(h[8],h[9]), pk2(h[10],h[11]), pk2(h[12],h[13]), pk2(h[14],h[15]));
        *(uint4*)(l_ql + slot0*1024 + srow*16) =
            make_uint4(pk2(l[0],l[1]), pk2(l[2],l[3]), pk2(l[4],l[5]), pk2(l[6],l[7]));
        *(uint4*)(l_ql + (slot0+1)*1024 + srow*16) =
            make_uint4(pk2(l[8],l[9]), pk2(l[10],l[11]), pk2(l[12],l[13]), pk2(l[14],l[15]));
    }

    // ---- kf staging helper: exp-scale, split, write to LDS buf ----
    auto STAGE_K = [&](int buf, int n) {
        unsigned char* const kh_b = lds + 16384 + buf * 16384;
        unsigned char* const kl_b = kh_b + 8192;
        float dv[16];
        #pragma unroll
        for (int g = 0; g < 4; ++g) {
            const float4 c4 = *(const float4*)&coff[cb + (size_t)(n + 1) * DHD + skc + g * 4];
            dv[g*4+0] = __expf(cm[g*4+0] - c4.x);
            dv[g*4+1] = __expf(cm[g*4+1] - c4.y);
            dv[g*4+2] = __expf(cm[g*4+2] - c4.z);
            dv[g*4+3] = __expf(cm[g*4+3] - c4.w);
        }
        const size_t kb = ((size_t)bh * LL + (size_t)n * QQ + srow) * DHD + skc;
        float v[16];
        #pragma unroll
        for (int g = 0; g < 4; ++g) {
            const float4 x4 = *(const float4*)&kf[kb + g * 4];
            v[g*4+0]=x4.x*dv[g*4+0]; v[g*4+1]=x4.y*dv[g*4+1];
            v[g*4+2]=x4.z*dv[g*4+2]; v[g*4+3]=x4.w*dv[g*4+3];
        }
        unsigned short h[16], l[16];
        #pragma unroll
        for (int i = 0; i < 16; ++i) bf16split(v[i], h[i], l[i]);
        *(uint4*)(kh_b + slot0*1024 + srow*16) =
            make_uint4(pk2(h[0],h[1]), pk2(h[2],h[3]), pk2(h[4],h[5]), pk2(h[6],h[7]));
        *(uint4*)(kh_b + (slot0+1)*1024 + srow*16) =
            make_uint4(pk2(h[8],h[9]), pk2(h[10],h[11]), pk2(h[12],h[13]), pk2(h[14],h[15]));
        *(uint4*)(kl_b + slot0*1024 + srow*16) =
            make_uint4(pk2(l[0],l[1]), pk2(l[2],l[3]), pk2(l[4],l[5]), pk2(l[6],l[7]));
        *(uint4*)(kl_b + (slot0+1)*1024 + srow*16) =
            make_uint4(pk2(l[8],l[9]), pk2(l[10],l[11]), pk2(l[12],l[13]), pk2(l[14],l[15]));
    };

    STAGE_K(0, n0);
    __syncthreads();

    int cur = 0;
    for (int n = n0; n < ne; ++n) {
        if (n + 1 < ne) STAGE_K(cur ^ 1, n + 1);   // prefetch next tile's kf

        const unsigned char* const kh_b = lds + 16384 + cur * 16384;
        const unsigned char* const kl_b = kh_b + 8192;

        f4 acc[2][2] = {};   // [ms: k-half][ns: q-half]
        #pragma unroll
        for (int ks = 0; ks < 2; ++ks) {
            const int ka = (ks * 4 + l4) * 1024;
            const s8b kh0 = *(const s8b*)(kh_b + ka + (wr      + l15) * 16);
            const s8b kh1 = *(const s8b*)(kh_b + ka + (wr + 16 + l15) * 16);
            const s8b kl0 = *(const s8b*)(kl_b + ka + (wr      + l15) * 16);
            const s8b kl1 = *(const s8b*)(kl_b + ka + (wr + 16 + l15) * 16);
            const s8b qh0 = *(const s8b*)(l_qh + ka + (wc      + l15) * 16);
            const s8b qh1 = *(const s8b*)(l_qh + ka + (wc + 16 + l15) * 16);
            const s8b ql0 = *(const s8b*)(l_ql + ka + (wc      + l15) * 16);
            const s8b ql1 = *(const s8b*)(l_ql + ka + (wc + 16 + l15) * 16);

            acc[0][0] = __builtin_amdgcn_mfma_f32_16x16x32_bf16(kh0, qh0, acc[0][0], 0, 0, 0);
            acc[0][1] = __builtin_amdgcn_mfma_f32_16x16x32_bf16(kh0, qh1, acc[0][1], 0, 0, 0);
            acc[1][0] = __builtin_amdgcn_mfma_f32_16x16x32_bf16(kh1, qh0, acc[1][0], 0, 0, 0);
            acc[1][1] = __builtin_amdgcn_mfma_f32_16x16x32_bf16(kh1, qh1, acc[1][1], 0, 0, 0);
            acc[0][0] = __builtin_amdgcn_mfma_f32_16x16x32_bf16(kh0, ql0, acc[0][0], 0, 0, 0);
            acc[0][1] = __builtin_amdgcn_mfma_f32_16x16x32_bf16(kh0, ql1, acc[0][1], 0, 0, 0);
            acc[1][0] = __builtin_amdgcn_mfma_f32_16x16x32_bf16(kh1, ql0, acc[1][0], 0, 0, 0);
            acc[1][1] = __builtin_amdgcn_mfma_f32_16x16x32_bf16(kh1, ql1, acc[1][1], 0, 0, 0);
            acc[0][0] = __builtin_amdgcn_mfma_f32_16x16x32_bf16(kl0, qh0, acc[0][0], 0, 0, 0);
            acc[0][1] = __builtin_amdgcn_mfma_f32_16x16x32_bf16(kl0, qh1, acc[0][1], 0, 0, 0);
            acc[1][0] = __builtin_amdgcn_mfma_f32_16x16x32_bf16(kl1, qh0, acc[1][0], 0, 0, 0);
            acc[1][1] = __builtin_amdgcn_mfma_f32_16x16x32_bf16(kl1, qh1, acc[1][1], 0, 0, 0);
        }

        // lane holds T[q][k0..k0+3]: q = wc+ns*16+l15, k0 = wr+ms*16+l4*4
        #pragma unroll
        for (int ms = 0; ms < 2; ++ms) {
            #pragma unroll
            for (int ns = 0; ns < 2; ++ns) {
                const int q  = wc + ns * 16 + l15;
                const int k0 = wr + ms * 16 + l4 * 4;
                *(float4*)&out[outbase + (size_t)q * LL + (size_t)n * QQ + k0] =
                    make_float4(acc[ms][ns][0], acc[ms][ns][1], acc[ms][ns][2], acc[ms][ns][3]);
            }
        }
        __syncthreads();   // staged n+1 visible; buf cur free for overwrite
        cur ^= 1;
    }
}

// ---------------------------------------------------------------------------
extern "C" void kernel_launch(void* const* d_in, const int* in_sizes, int n_in,
                              void* d_out, int out_size, void* d_ws, size_t ws_size,
                              hipStream_t stream) {
    const float* x  = (const float*)d_in[0];
    const float* Wa = (const float*)d_in[1];
    const float* ba = (const float*)d_in[2];
    const float* Wb = (const float*)d_in[3];
    const float* bb = (const float*)d_in[4];
    const float* Wc = (const float*)d_in[5];
    const float* bc = (const float*)d_in[6];
    float* out = (float*)d_out;
    float* ws  = (float*)d_ws;

    const size_t NBLD = (size_t)BB * LL * DD;   // 1,048,576 floats
    float* logA = ws;
    float* Bf   = ws + 1 * NBLD;
    float* Cf   = ws + 2 * NBLD;
    // slot 3 (old Sl) now holds only the bf16 split staging arrays
    float* qf   = ws + 4 * NBLD;
    float* kf   = ws + 5 * NBLD;
    float* coff = ws + 6 * NBLD;                        // 16*17*64 floats
    float* csum = coff + (size_t)BB * HH * 17 * DHD;    // 256*64 floats

    unsigned short* xh  = (unsigned short*)(ws + 3 * NBLD);
    unsigned short* xl  = xh + 1048576;
    unsigned short* whp = xl + 1048576;    // 3 x 262144 (overlaps qf region,
    unsigned short* wlp = whp + 786432;    //  consumed before scan writes qf)

    convert_split<<<1792, 256, 0, stream>>>(x, Wa, Wb, Wc, xh, xl, whp, wlp);
    gemm3_fused<<<256, 512, 0, stream>>>(xh, xl, whp, wlp, ba, bb, bc, logA, Bf, Cf, csum);
    scan_diag<<<BB * HH * NCC, 256, 0, stream>>>(logA, Bf, Cf, csum, qf, kf, coff, out);
    band_row<<<BB * HH * NCC * 2, 256, 0, stream>>>(qf, kf, coff, out);
}

// Round 12
// 81.776 us; speedup vs baseline: 1.2356x; 1.1399x over previous
//
#include <hip/hip_runtime.h>
#include <math.h>

#define BB 2
#define LL 1024
#define DD 512
#define HH 8
#define DHD 64
#define QQ 64
#define NCC 16

typedef __attribute__((ext_vector_type(8))) short s8b;   // 8 bf16 (4 VGPRs)
typedef __attribute__((ext_vector_type(4))) float f4;    // 4 fp32 acc

__device__ __forceinline__ void gld16(const void* g, void* l) {
    __builtin_amdgcn_global_load_lds(
        (const __attribute__((address_space(1))) unsigned int*)g,
        (__attribute__((address_space(3))) unsigned int*)l, 16, 0, 0);
}

__device__ __forceinline__ void bf16split(float f, unsigned short& h, unsigned short& l) {
    unsigned u  = __float_as_uint(f);
    unsigned hb = (u + 0x7FFFu + ((u >> 16) & 1u)) & 0xFFFF0000u;   // RTNE bf16
    float fh = __uint_as_float(hb);
    float fl = f - fh;
    unsigned ul = __float_as_uint(fl);
    unsigned lb = (ul + 0x7FFFu + ((ul >> 16) & 1u)) >> 16;
    h = (unsigned short)(hb >> 16);
    l = (unsigned short)lb;
}

__device__ __forceinline__ unsigned pk2(unsigned short a, unsigned short b) {
    return (unsigned)a | ((unsigned)b << 16);
}

// ---------------------------------------------------------------------------
// Kernel 0: split x / Wa / Wb / Wc into bf16 hi/lo arrays (unchanged).
// ---------------------------------------------------------------------------
__global__ __launch_bounds__(256) void convert_split(
    const float* __restrict__ x, const float* __restrict__ Wa,
    const float* __restrict__ Wb, const float* __restrict__ Wc,
    unsigned short* __restrict__ xh, unsigned short* __restrict__ xl,
    unsigned short* __restrict__ wh, unsigned short* __restrict__ wl)
{
    const int g = blockIdx.x * 256 + threadIdx.x;    // float4 index
    const float* src;
    unsigned short *dh, *dl;
    if (g < 262144) {
        const size_t off = (size_t)g * 4;
        src = x + off; dh = xh + off; dl = xl + off;
    } else {
        const size_t j = (size_t)(g - 262144) * 4;   // 0..786431
        const int wsel = (int)(j >> 18);             // 262144 elements each
        const size_t r = j & 262143;
        src = (wsel == 0 ? Wa : (wsel == 1 ? Wb : Wc)) + r;
        dh = wh + j; dl = wl + j;
    }
    const float4 v = *(const float4*)src;
    const float f[4] = {v.x, v.y, v.z, v.w};
    unsigned short h[4], l[4];
    #pragma unroll
    for (int i = 0; i < 4; ++i) bf16split(f[i], h[i], l[i]);
    *(uint2*)dh = make_uint2(pk2(h[0], h[1]), pk2(h[2], h[3]));
    *(uint2*)dl = make_uint2(pk2(l[0], l[1]), pk2(l[2], l[3]));
}

// ---------------------------------------------------------------------------
// Kernel 1: fused 3-weight MFMA GEMM, double-buffered, + csum epilogue.
// NEW staging: coalesced global reads. Call s covers rows [16s,16s+16) x all
// 4 k-chunks: lane l -> row 16s+(l>>2), fetches k-chunk ((l&3) ^ ((row>>1)&3))
// (swizzle keeps reader's ds_read at <=2-way bank aliasing, which is free).
// LDS tile layout: [64 rows][4 slots][16 B]; slot s holds k-chunk s^swz(row).
// ---------------------------------------------------------------------------
__global__ __launch_bounds__(512) void gemm3_fused(
    const unsigned short* __restrict__ xh, const unsigned short* __restrict__ xl,
    const unsigned short* __restrict__ wh, const unsigned short* __restrict__ wl,
    const float* __restrict__ ba, const float* __restrict__ bb, const float* __restrict__ bc,
    float* __restrict__ logA, float* __restrict__ Bf, float* __restrict__ Cf,
    float* __restrict__ csum)
{
    __shared__ unsigned char lds[65536];
    __shared__ float csv[64];

    const int bm = blockIdx.x >> 3;
    const int bn = blockIdx.x & 7;
    const int m0 = bm << 6, o0 = bn << 6;
    const int t = threadIdx.x, wv = t >> 6, ln = t & 63;
    const int l15 = ln & 15, l4 = ln >> 4;
    const int wr = (wv >> 2) << 5;      // 0 / 32
    const int wc = (wv & 3) << 4;       // 0 / 16 / 32 / 48

    // staging: wave wv owns array wv (0=xh,1=xl,2=wh0,3=wl0,4=wh1,5=wl1,6=wh2,7=wl2)
    const unsigned short* hp = (wv < 2) ? xh : wh + (size_t)((wv - 2) >> 1) * 262144;
    const unsigned short* lp = (wv < 2) ? xl : wl + (size_t)((wv - 2) >> 1) * 262144;
    const unsigned short* sp2 = ((wv & 1) ? lp : hp) + (size_t)((wv < 2) ? m0 : o0) * DD;
    const int abase = wv * 4096;

    // per-call coalesced offsets: lane -> (row, swizzled k-chunk)
    const int rl = ln >> 2;          // row within 16-row group
    const int sl = ln & 3;           // stored slot
    size_t gofs[4];
    #pragma unroll
    for (int s = 0; s < 4; ++s) {
        const int rowg = s * 16 + rl;
        const int kfc  = sl ^ ((rowg >> 1) & 3);
        gofs[s] = (size_t)rowg * DD + kfc * 8;
    }

    f4 acc[3][2] = {};

    auto STAGE = [&](int buf, int kt) {
        unsigned char* base = lds + buf * 32768 + abase;
        #pragma unroll
        for (int s = 0; s < 4; ++s)
            gld16(sp2 + kt + gofs[s], base + s * 1024);
    };

    // LDS byte offset of (row, k-group kg) within a 4 KB array tile
    auto ldso = [&](int row, int kg) {
        return row * 64 + ((kg ^ ((row >> 1) & 3)) << 4);
    };

    auto COMPUTE = [&](int buf) {
        const unsigned char* base = lds + buf * 32768;
        const s8b ah0 = *(const s8b*)(base + 0*4096 + ldso(wr      + l15, l4));
        const s8b ah1 = *(const s8b*)(base + 0*4096 + ldso(wr + 16 + l15, l4));
        const s8b al0 = *(const s8b*)(base + 1*4096 + ldso(wr      + l15, l4));
        const s8b al1 = *(const s8b*)(base + 1*4096 + ldso(wr + 16 + l15, l4));
        #pragma unroll
        for (int s = 0; s < 3; ++s) {
            const s8b bh = *(const s8b*)(base + (2 + 2*s)*4096 + ldso(wc + l15, l4));
            const s8b bl = *(const s8b*)(base + (3 + 2*s)*4096 + ldso(wc + l15, l4));
            acc[s][0] = __builtin_amdgcn_mfma_f32_16x16x32_bf16(ah0, bh, acc[s][0], 0, 0, 0);
            acc[s][1] = __builtin_amdgcn_mfma_f32_16x16x32_bf16(ah1, bh, acc[s][1], 0, 0, 0);
            acc[s][0] = __builtin_amdgcn_mfma_f32_16x16x32_bf16(ah0, bl, acc[s][0], 0, 0, 0);
            acc[s][1] = __builtin_amdgcn_mfma_f32_16x16x32_bf16(ah1, bl, acc[s][1], 0, 0, 0);
            acc[s][0] = __builtin_amdgcn_mfma_f32_16x16x32_bf16(al0, bh, acc[s][0], 0, 0, 0);
            acc[s][1] = __builtin_amdgcn_mfma_f32_16x16x32_bf16(al1, bh, acc[s][1], 0, 0, 0);
        }
    };

    STAGE(0, 0);
    __syncthreads();
    int cur = 0;
    for (int it = 0; it < 16; ++it) {
        if (it < 15) STAGE(cur ^ 1, (it + 1) * 32);
        COMPUTE(cur);
        __syncthreads();
        cur ^= 1;
    }

    const int col = o0 + wc + l15;
    const float bva = ba[col], bvb = bb[col], bvc = bc[col];
    float asum = 0.f;
    #pragma unroll
    for (int ms = 0; ms < 2; ++ms) {
        const int row0 = m0 + wr + ms * 16 + l4 * 4;
        #pragma unroll
        for (int r = 0; r < 4; ++r) {
            const size_t o = (size_t)(row0 + r) * DD + col;
            float va = acc[0][ms][r] + bva;
            va = fminf(va, 0.f) - log1pf(__expf(-fabsf(va)));   // logsigmoid
            logA[o] = va;
            asum += va;
            Bf[o] = acc[1][ms][r] + bvb;
            Cf[o] = acc[2][ms][r] + bvc;
        }
    }

    // column-sum of the logsigmoid tile -> csum[chunk][d]
    asum += __shfl_xor(asum, 16);
    asum += __shfl_xor(asum, 32);
    if (wv < 4 && l4 == 0) csv[wc + l15] = asum;
    __syncthreads();
    if (wv >= 4 && l4 == 0) {
        const int blkc = (((bm >> 4) * 8 + bn) << 4) + (bm & 15);   // (b*8+h)*16+c
        csum[(size_t)blkc * DHD + wc + l15] = csv[wc + l15] + asum;
    }
}

// ---------------------------------------------------------------------------
// Kernel 2: scan + fused diag tile (logA cached in regs between phases).
// ---------------------------------------------------------------------------
__global__ __launch_bounds__(256) void scan_diag(
    const float* __restrict__ logA, const float* __restrict__ Bf,
    const float* __restrict__ Cf, const float* __restrict__ csum,
    float* __restrict__ qf, float* __restrict__ kf,
    float* __restrict__ coff, float* __restrict__ out)
{
    __shared__ float part[4][DHD];
    __shared__ float smA[DHD][65];   // Cf stash [d][row]
    __shared__ float smB[DHD][65];   // Bf stash
    __shared__ float smC[DHD][65];   // Sloc stash

    const int blk = blockIdx.x;
    const int bh = blk >> 4, c = blk & 15;
    const int b = bh >> 3, h = bh & 7;
    const int t = threadIdx.x;
    const int d = t & 63, w = t >> 6;

    const size_t gbase = (size_t)(b * LL + c * QQ + w * 16) * DD + h * DHD + d;
    float lar[16];
    float ps = 0.f;
    #pragma unroll
    for (int i = 0; i < 16; ++i) {
        lar[i] = logA[gbase + (size_t)i * DD];
        ps += lar[i];
    }
    part[w][d] = ps;
    __syncthreads();

    const size_t cs0 = ((size_t)bh << 4) * DHD + d;
    float off = 0.f;
    for (int cc = 0; cc < c; ++cc) off += csum[cs0 + (size_t)cc * DHD];
    const float tot = part[0][d] + part[1][d] + part[2][d] + part[3][d];
    if (t < DHD) {
        coff[((size_t)bh * 17 + c) * DHD + t] = off;
        if (c == NCC - 1) coff[((size_t)bh * 17 + 16) * DHD + t] = off + tot;
    }

    float run = 0.f;
    for (int ww = 0; ww < 4; ++ww) if (ww < w) run += part[ww][d];

    const size_t hbase = ((size_t)bh * LL + c * QQ + w * 16) * DHD + d;
    #pragma unroll
    for (int i = 0; i < 16; ++i) {
        const size_t gi = gbase + (size_t)i * DD;
        const float cv = Cf[gi];
        const float bv = Bf[gi];
        qf[hbase + (size_t)i * DHD] = cv * __expf(run);       // exp(Sm1 - Eprev)
        run += lar[i];
        const int rloc = w * 16 + i;
        smC[d][rloc] = run;       // Sloc
        smA[d][rloc] = cv;        // C
        smB[d][rloc] = bv;        // B
        kf[hbase + (size_t)i * DHD] = bv * __expf(tot - run); // exp(E - S)
    }
    __syncthreads();

    // ---- diag tile compute (R8 body, fed from LDS stash) ----
    const int q0 = ((t >> 4) & 15) << 2;
    const int k0 = (t & 15) << 2;

    float acc[4][4] = {};
    if (q0 + 3 >= k0) {
        #pragma unroll 2
        for (int dd = 0; dd < DHD; ++dd) {
            const float4 cq = *(const float4*)&smA[dd][q0];
            const float4 bk = *(const float4*)&smB[dd][k0];
            const float4 sk = *(const float4*)&smC[dd][k0];
            const float cqa[4] = {cq.x, cq.y, cq.z, cq.w};
            const float bka[4] = {bk.x, bk.y, bk.z, bk.w};
            const float ska[4] = {sk.x, sk.y, sk.z, sk.w};
            float s1a[4];
            #pragma unroll
            for (int i = 0; i < 4; ++i) {
                const int qi = q0 + i;
                s1a[i] = (qi == 0) ? 0.f : smC[dd][qi - 1];
            }
            #pragma unroll
            for (int i = 0; i < 4; ++i) {
                #pragma unroll
                for (int j = 0; j < 4; ++j) {
                    const int qi = q0 + i, kj = k0 + j;
                    const float wgt = (qi > kj) ? __expf(s1a[i] - ska[j])
                                                : ((qi == kj) ? 1.f : 0.f);
                    acc[i][j] += cqa[i] * wgt * bka[j];
                }
            }
        }
    }
    const size_t outrow0 = ((size_t)bh * LL + (size_t)c * QQ) * LL + (size_t)c * QQ;
    #pragma unroll
    for (int i = 0; i < 4; ++i)
        *(float4*)&out[outrow0 + (size_t)(q0 + i) * LL + k0] =
            make_float4(acc[i][0], acc[i][1], acc[i][2], acc[i][3]);
}

// ---------------------------------------------------------------------------
// Kernel 3: band v3 (R8 exact). Block = (bh, m, half); n in [8*half, 8*half+8).
// ---------------------------------------------------------------------------
__global__ __launch_bounds__(256) void band_row(
    const float* __restrict__ qf, const float* __restrict__ kf,
    const float* __restrict__ coff, float* __restrict__ out)
{
    __shared__ unsigned char lds[49152];
    unsigned char* const l_qh = lds;
    unsigned char* const l_ql = lds + 8192;
    // k buffers: base 16384 + buf*16384, kh at +0, kl at +8192

    const int half = blockIdx.x & 1;
    const int m    = (blockIdx.x >> 1) & 15;
    const int bh   = blockIdx.x >> 5;
    const int n0   = half << 3;

    const int t  = threadIdx.x;
    const int wv = t >> 6;
    const int ln = t & 63;
    const int l15 = ln & 15;
    const int l4  = ln >> 4;
    const int wr = (wv >> 1) << 5;           // k-side half (A operand)
    const int wc = (wv & 1) << 5;            // q-side half (B operand)

    const int srow = t >> 2;                 // 0..63
    const int skc  = (t & 3) << 4;           // 0/16/32/48
    const int slot0 = skc >> 3;

    const size_t cb = (size_t)bh * 17 * DHD;
    const size_t outbase = ((size_t)bh * LL + (size_t)m * QQ) * LL;

    // ---- zero tiles (n > m within range), no LDS involved ----
    for (int n = (m >= n0 ? m + 1 : n0); n < n0 + 8; ++n) {
        const size_t ob = outbase + (size_t)srow * LL + (size_t)n * QQ + skc;
        const float4 z = make_float4(0.f, 0.f, 0.f, 0.f);
        *(float4*)&out[ob + 0]  = z;
        *(float4*)&out[ob + 4]  = z;
        *(float4*)&out[ob + 8]  = z;
        *(float4*)&out[ob + 12] = z;
    }

    const int ne = (m < n0 + 8) ? m : (n0 + 8);   // offdiag n in [n0, ne)
    if (n0 >= ne) return;

    // ---- coff[m] slice for this thread's 16 k-columns ----
    float cm[16];
    #pragma unroll
    for (int g = 0; g < 4; ++g) {
        const float4 a = *(const float4*)&coff[cb + (size_t)m * DHD + skc + g * 4];
        cm[g*4+0]=a.x; cm[g*4+1]=a.y; cm[g*4+2]=a.z; cm[g*4+3]=a.w;
    }

    // ---- stage qf_m once (hi/lo split) ----
    {
        const size_t qb = ((size_t)bh * LL + (size_t)m * QQ + srow) * DHD + skc;
        float v[16];
        #pragma unroll
        for (int g = 0; g < 4; ++g) {
            const float4 x4 = *(const float4*)&qf[qb + g * 4];
            v[g*4+0]=x4.x; v[g*4+1]=x4.y; v[g*4+2]=x4.z; v[g*4+3]=x4.w;
        }
        unsigned short h[16], l[16];
        #pragma unroll
        for (int i = 0; i < 16; ++i) bf16split(v[i], h[i], l[i]);
        *(uint4*)(l_qh + slot0*1024 + srow*16) =
            make_uint4(pk2(h[0],h[1]), pk2(h[2],h[3]), pk2(h[4],h[5]), pk2(h[6],h[7]));
        *(uint4*)(l_qh + (slot0+1)*1024 + srow*16) =
            make_uint4(pk2(h[8],h[9]), pk2(h[10],h[11]), pk2(h[12],h[13]), pk2(h[14],h[15]));
        *(uint4*)(l_ql + slot0*1024 + srow*16) =
            make_uint4(pk2(l[0],l[1]), pk2(l[2],l[3]), pk2(l[4],l[5]), pk2(l[6],l[7]));
        *(uint4*)(l_ql + (slot0+1)*1024 + srow*16) =
            make_uint4(pk2(l[8],l[9]), pk2(l[10],l[11]), pk2(l[12],l[13]), pk2(l[14],l[15]));
    }

    // ---- kf staging helper: exp-scale, split, write to LDS buf ----
    auto STAGE_K = [&](int buf, int n) {
        unsigned char* const kh_b = lds + 16384 + buf * 16384;
        unsigned char* const kl_b = kh_b + 8192;
        float dv[16];
        #pragma unroll
        for (int g = 0; g < 4; ++g) {
            const float4 c4 = *(const float4*)&coff[cb + (size_t)(n + 1) * DHD + skc + g * 4];
            dv[g*4+0] = __expf(cm[g*4+0] - c4.x);
            dv[g*4+1] = __expf(cm[g*4+1] - c4.y);
            dv[g*4+2] = __expf(cm[g*4+2] - c4.z);
            dv[g*4+3] = __expf(cm[g*4+3] - c4.w);
        }
        const size_t kb = ((size_t)bh * LL + (size_t)n * QQ + srow) * DHD + skc;
        float v[16];
        #pragma unroll
        for (int g = 0; g < 4; ++g) {
            const float4 x4 = *(const float4*)&kf[kb + g * 4];
            v[g*4+0]=x4.x*dv[g*4+0]; v[g*4+1]=x4.y*dv[g*4+1];
            v[g*4+2]=x4.z*dv[g*4+2]; v[g*4+3]=x4.w*dv[g*4+3];
        }
        unsigned short h[16], l[16];
        #pragma unroll
        for (int i = 0; i < 16; ++i) bf16split(v[i], h[i], l[i]);
        *(uint4*)(kh_b + slot0*1024 + srow*16) =
            make_uint4(pk2(h[0],h[1]), pk2(h[2],h[3]), pk2(h[4],h[5]), pk2(h[6],h[7]));
        *(uint4*)(kh_b + (slot0+1)*1024 + srow*16) =
            make_uint4(pk2(h[8],h[9]), pk2(h[10],h[11]), pk2(h[12],h[13]), pk2(h[14],h[15]));
        *(uint4*)(kl_b + slot0*1024 + srow*16) =
            make_uint4(pk2(l[0],l[1]), pk2(l[2],l[3]), pk2(l[4],l[5]), pk2(l[6],l[7]));
        *(uint4*)(kl_b + (slot0+1)*1024 + srow*16) =
            make_uint4(pk2(l[8],l[9]), pk2(l[10],l[11]), pk2(l[12],l[13]), pk2(l[14],l[15]));
    };

    STAGE_K(0, n0);
    __syncthreads();

    int cur = 0;
    for (int n = n0; n < ne; ++n) {
        if (n + 1 < ne) STAGE_K(cur ^ 1, n + 1);   // prefetch next tile's kf

        const unsigned char* const kh_b = lds + 16384 + cur * 16384;
        const unsigned char* const kl_b = kh_b + 8192;

        f4 acc[2][2] = {};   // [ms: k-half][ns: q-half]
        #pragma unroll
        for (int ks = 0; ks < 2; ++ks) {
            const int ka = (ks * 4 + l4) * 1024;
            const s8b kh0 = *(const s8b*)(kh_b + ka + (wr      + l15) * 16);
            const s8b kh1 = *(const s8b*)(kh_b + ka + (wr + 16 + l15) * 16);
            const s8b kl0 = *(const s8b*)(kl_b + ka + (wr      + l15) * 16);
            const s8b kl1 = *(const s8b*)(kl_b + ka + (wr + 16 + l15) * 16);
            const s8b qh0 = *(const s8b*)(l_qh + ka + (wc      + l15) * 16);
            const s8b qh1 = *(const s8b*)(l_qh + ka + (wc + 16 + l15) * 16);
            const s8b ql0 = *(const s8b*)(l_ql + ka + (wc      + l15) * 16);
            const s8b ql1 = *(const s8b*)(l_ql + ka + (wc + 16 + l15) * 16);

            acc[0][0] = __builtin_amdgcn_mfma_f32_16x16x32_bf16(kh0, qh0, acc[0][0], 0, 0, 0);
            acc[0][1] = __builtin_amdgcn_mfma_f32_16x16x32_bf16(kh0, qh1, acc[0][1], 0, 0, 0);
            acc[1][0] = __builtin_amdgcn_mfma_f32_16x16x32_bf16(kh1, qh0, acc[1][0], 0, 0, 0);
            acc[1][1] = __builtin_amdgcn_mfma_f32_16x16x32_bf16(kh1, qh1, acc[1][1], 0, 0, 0);
            acc[0][0] = __builtin_amdgcn_mfma_f32_16x16x32_bf16(kh0, ql0, acc[0][0], 0, 0, 0);
            acc[0][1] = __builtin_amdgcn_mfma_f32_16x16x32_bf16(kh0, ql1, acc[0][1], 0, 0, 0);
            acc[1][0] = __builtin_amdgcn_mfma_f32_16x16x32_bf16(kh1, ql0, acc[1][0], 0, 0, 0);
            acc[1][1] = __builtin_amdgcn_mfma_f32_16x16x32_bf16(kh1, ql1, acc[1][1], 0, 0, 0);
            acc[0][0] = __builtin_amdgcn_mfma_f32_16x16x32_bf16(kl0, qh0, acc[0][0], 0, 0, 0);
            acc[0][1] = __builtin_amdgcn_mfma_f32_16x16x32_bf16(kl0, qh1, acc[0][1], 0, 0, 0);
            acc[1][0] = __builtin_amdgcn_mfma_f32_16x16x32_bf16(kl1, qh0, acc[1][0], 0, 0, 0);
            acc[1][1] = __builtin_amdgcn_mfma_f32_16x16x32_bf16(kl1, qh1, acc[1][1], 0, 0, 0);
        }

        // lane holds T[q][k0..k0+3]: q = wc+ns*16+l15, k0 = wr+ms*16+l4*4
        #pragma unroll
        for (int ms = 0; ms < 2; ++ms) {
            #pragma unroll
            for (int ns = 0; ns < 2; ++ns) {
                const int q  = wc + ns * 16 + l15;
                const int k0 = wr + ms * 16 + l4 * 4;
                *(float4*)&out[outbase + (size_t)q * LL + (size_t)n * QQ + k0] =
                    make_float4(acc[ms][ns][0], acc[ms][ns][1], acc[ms][ns][2], acc[ms][ns][3]);
            }
        }
        __syncthreads();   // staged n+1 visible; buf cur free for overwrite
        cur ^= 1;
    }
}

// ---------------------------------------------------------------------------
extern "C" void kernel_launch(void* const* d_in, const int* in_sizes, int n_in,
                              void* d_out, int out_size, void* d_ws, size_t ws_size,
                              hipStream_t stream) {
    const float* x  = (const float*)d_in[0];
    const float* Wa = (const float*)d_in[1];
    const float* ba = (const float*)d_in[2];
    const float* Wb = (const float*)d_in[3];
    const float* bb = (const float*)d_in[4];
    const float* Wc = (const float*)d_in[5];
    const float* bc = (const float*)d_in[6];
    float* out = (float*)d_out;
    float* ws  = (float*)d_ws;

    const size_t NBLD = (size_t)BB * LL * DD;   // 1,048,576 floats
    float* logA = ws;
    float* Bf   = ws + 1 * NBLD;
    float* Cf   = ws + 2 * NBLD;
    // slot 3 holds the bf16 split staging arrays
    float* qf   = ws + 4 * NBLD;
    float* kf   = ws + 5 * NBLD;
    float* coff = ws + 6 * NBLD;                        // 16*17*64 floats
    float* csum = coff + (size_t)BB * HH * 17 * DHD;    // 256*64 floats

    unsigned short* xh  = (unsigned short*)(ws + 3 * NBLD);
    unsigned short* xl  = xh + 1048576;
    unsigned short* whp = xl + 1048576;    // 3 x 262144 (overlaps qf region,
    unsigned short* wlp = whp + 786432;    //  consumed before scan writes qf)

    convert_split<<<1792, 256, 0, stream>>>(x, Wa, Wb, Wc, xh, xl, whp, wlp);
    gemm3_fused<<<256, 512, 0, stream>>>(xh, xl, whp, wlp, ba, bb, bc, logA, Bf, Cf, csum);
    scan_diag<<<BB * HH * NCC, 256, 0, stream>>>(logA, Bf, Cf, csum, qf, kf, coff, out);
    band_row<<<BB * HH * NCC * 2, 256, 0, stream>>>(qf, kf, coff, out);
}

// Round 13
// 81.489 us; speedup vs baseline: 1.2399x; 1.0035x over previous
//
#include <hip/hip_runtime.h>
#include <math.h>

#define BB 2
#define LL 1024
#define DD 512
#define HH 8
#define DHD 64
#define QQ 64
#define NCC 16

typedef __attribute__((ext_vector_type(8))) short s8b;   // 8 bf16 (4 VGPRs)
typedef __attribute__((ext_vector_type(4))) float f4;    // 4 fp32 acc

__device__ __forceinline__ void gld16(const void* g, void* l) {
    __builtin_amdgcn_global_load_lds(
        (const __attribute__((address_space(1))) unsigned int*)g,
        (__attribute__((address_space(3))) unsigned int*)l, 16, 0, 0);
}

__device__ __forceinline__ void bf16split(float f, unsigned short& h, unsigned short& l) {
    unsigned u  = __float_as_uint(f);
    unsigned hb = (u + 0x7FFFu + ((u >> 16) & 1u)) & 0xFFFF0000u;   // RTNE bf16
    float fh = __uint_as_float(hb);
    float fl = f - fh;
    unsigned ul = __float_as_uint(fl);
    unsigned lb = (ul + 0x7FFFu + ((ul >> 16) & 1u)) >> 16;
    h = (unsigned short)(hb >> 16);
    l = (unsigned short)lb;
}

__device__ __forceinline__ unsigned pk2(unsigned short a, unsigned short b) {
    return (unsigned)a | ((unsigned)b << 16);
}

// ---------------------------------------------------------------------------
// Kernel 0: split x / Wa / Wb / Wc into bf16 hi/lo arrays (unchanged).
// ---------------------------------------------------------------------------
__global__ __launch_bounds__(256) void convert_split(
    const float* __restrict__ x, const float* __restrict__ Wa,
    const float* __restrict__ Wb, const float* __restrict__ Wc,
    unsigned short* __restrict__ xh, unsigned short* __restrict__ xl,
    unsigned short* __restrict__ wh, unsigned short* __restrict__ wl)
{
    const int g = blockIdx.x * 256 + threadIdx.x;    // float4 index
    const float* src;
    unsigned short *dh, *dl;
    if (g < 262144) {
        const size_t off = (size_t)g * 4;
        src = x + off; dh = xh + off; dl = xl + off;
    } else {
        const size_t j = (size_t)(g - 262144) * 4;   // 0..786431
        const int wsel = (int)(j >> 18);             // 262144 elements each
        const size_t r = j & 262143;
        src = (wsel == 0 ? Wa : (wsel == 1 ? Wb : Wc)) + r;
        dh = wh + j; dl = wl + j;
    }
    const float4 v = *(const float4*)src;
    const float f[4] = {v.x, v.y, v.z, v.w};
    unsigned short h[4], l[4];
    #pragma unroll
    for (int i = 0; i < 4; ++i) bf16split(f[i], h[i], l[i]);
    *(uint2*)dh = make_uint2(pk2(h[0], h[1]), pk2(h[2], h[3]));
    *(uint2*)dl = make_uint2(pk2(l[0], l[1]), pk2(l[2], l[3]));
}

// ---------------------------------------------------------------------------
// Kernel 1: fused 3-weight MFMA GEMM, double-buffered, + csum epilogue
// (unchanged from R12: coalesced swizzled staging).
// ---------------------------------------------------------------------------
__global__ __launch_bounds__(512) void gemm3_fused(
    const unsigned short* __restrict__ xh, const unsigned short* __restrict__ xl,
    const unsigned short* __restrict__ wh, const unsigned short* __restrict__ wl,
    const float* __restrict__ ba, const float* __restrict__ bb, const float* __restrict__ bc,
    float* __restrict__ logA, float* __restrict__ Bf, float* __restrict__ Cf,
    float* __restrict__ csum)
{
    __shared__ unsigned char lds[65536];
    __shared__ float csv[64];

    const int bm = blockIdx.x >> 3;
    const int bn = blockIdx.x & 7;
    const int m0 = bm << 6, o0 = bn << 6;
    const int t = threadIdx.x, wv = t >> 6, ln = t & 63;
    const int l15 = ln & 15, l4 = ln >> 4;
    const int wr = (wv >> 2) << 5;      // 0 / 32
    const int wc = (wv & 3) << 4;       // 0 / 16 / 32 / 48

    const unsigned short* hp = (wv < 2) ? xh : wh + (size_t)((wv - 2) >> 1) * 262144;
    const unsigned short* lp = (wv < 2) ? xl : wl + (size_t)((wv - 2) >> 1) * 262144;
    const unsigned short* sp2 = ((wv & 1) ? lp : hp) + (size_t)((wv < 2) ? m0 : o0) * DD;
    const int abase = wv * 4096;

    const int rl = ln >> 2;          // row within 16-row group
    const int sl = ln & 3;           // stored slot
    size_t gofs[4];
    #pragma unroll
    for (int s = 0; s < 4; ++s) {
        const int rowg = s * 16 + rl;
        const int kfc  = sl ^ ((rowg >> 1) & 3);
        gofs[s] = (size_t)rowg * DD + kfc * 8;
    }

    f4 acc[3][2] = {};

    auto STAGE = [&](int buf, int kt) {
        unsigned char* base = lds + buf * 32768 + abase;
        #pragma unroll
        for (int s = 0; s < 4; ++s)
            gld16(sp2 + kt + gofs[s], base + s * 1024);
    };

    auto ldso = [&](int row, int kg) {
        return row * 64 + ((kg ^ ((row >> 1) & 3)) << 4);
    };

    auto COMPUTE = [&](int buf) {
        const unsigned char* base = lds + buf * 32768;
        const s8b ah0 = *(const s8b*)(base + 0*4096 + ldso(wr      + l15, l4));
        const s8b ah1 = *(const s8b*)(base + 0*4096 + ldso(wr + 16 + l15, l4));
        const s8b al0 = *(const s8b*)(base + 1*4096 + ldso(wr      + l15, l4));
        const s8b al1 = *(const s8b*)(base + 1*4096 + ldso(wr + 16 + l15, l4));
        #pragma unroll
        for (int s = 0; s < 3; ++s) {
            const s8b bh = *(const s8b*)(base + (2 + 2*s)*4096 + ldso(wc + l15, l4));
            const s8b bl = *(const s8b*)(base + (3 + 2*s)*4096 + ldso(wc + l15, l4));
            acc[s][0] = __builtin_amdgcn_mfma_f32_16x16x32_bf16(ah0, bh, acc[s][0], 0, 0, 0);
            acc[s][1] = __builtin_amdgcn_mfma_f32_16x16x32_bf16(ah1, bh, acc[s][1], 0, 0, 0);
            acc[s][0] = __builtin_amdgcn_mfma_f32_16x16x32_bf16(ah0, bl, acc[s][0], 0, 0, 0);
            acc[s][1] = __builtin_amdgcn_mfma_f32_16x16x32_bf16(ah1, bl, acc[s][1], 0, 0, 0);
            acc[s][0] = __builtin_amdgcn_mfma_f32_16x16x32_bf16(al0, bh, acc[s][0], 0, 0, 0);
            acc[s][1] = __builtin_amdgcn_mfma_f32_16x16x32_bf16(al1, bh, acc[s][1], 0, 0, 0);
        }
    };

    STAGE(0, 0);
    __syncthreads();
    int cur = 0;
    for (int it = 0; it < 16; ++it) {
        if (it < 15) STAGE(cur ^ 1, (it + 1) * 32);
        COMPUTE(cur);
        __syncthreads();
        cur ^= 1;
    }

    const int col = o0 + wc + l15;
    const float bva = ba[col], bvb = bb[col], bvc = bc[col];
    float asum = 0.f;
    #pragma unroll
    for (int ms = 0; ms < 2; ++ms) {
        const int row0 = m0 + wr + ms * 16 + l4 * 4;
        #pragma unroll
        for (int r = 0; r < 4; ++r) {
            const size_t o = (size_t)(row0 + r) * DD + col;
            float va = acc[0][ms][r] + bva;
            va = fminf(va, 0.f) - log1pf(__expf(-fabsf(va)));   // logsigmoid
            logA[o] = va;
            asum += va;
            Bf[o] = acc[1][ms][r] + bvb;
            Cf[o] = acc[2][ms][r] + bvc;
        }
    }

    asum += __shfl_xor(asum, 16);
    asum += __shfl_xor(asum, 32);
    if (wv < 4 && l4 == 0) csv[wc + l15] = asum;
    __syncthreads();
    if (wv >= 4 && l4 == 0) {
        const int blkc = (((bm >> 4) * 8 + bn) << 4) + (bm & 15);   // (b*8+h)*16+c
        csum[(size_t)blkc * DHD + wc + l15] = csv[wc + l15] + asum;
    }
}

// ---------------------------------------------------------------------------
// Kernel 2: scan + fused diag tile (unchanged from R12).
// ---------------------------------------------------------------------------
__global__ __launch_bounds__(256) void scan_diag(
    const float* __restrict__ logA, const float* __restrict__ Bf,
    const float* __restrict__ Cf, const float* __restrict__ csum,
    float* __restrict__ qf, float* __restrict__ kf,
    float* __restrict__ coff, float* __restrict__ out)
{
    __shared__ float part[4][DHD];
    __shared__ float smA[DHD][65];   // Cf stash [d][row]
    __shared__ float smB[DHD][65];   // Bf stash
    __shared__ float smC[DHD][65];   // Sloc stash

    const int blk = blockIdx.x;
    const int bh = blk >> 4, c = blk & 15;
    const int b = bh >> 3, h = bh & 7;
    const int t = threadIdx.x;
    const int d = t & 63, w = t >> 6;

    const size_t gbase = (size_t)(b * LL + c * QQ + w * 16) * DD + h * DHD + d;
    float lar[16];
    float ps = 0.f;
    #pragma unroll
    for (int i = 0; i < 16; ++i) {
        lar[i] = logA[gbase + (size_t)i * DD];
        ps += lar[i];
    }
    part[w][d] = ps;
    __syncthreads();

    const size_t cs0 = ((size_t)bh << 4) * DHD + d;
    float off = 0.f;
    for (int cc = 0; cc < c; ++cc) off += csum[cs0 + (size_t)cc * DHD];
    const float tot = part[0][d] + part[1][d] + part[2][d] + part[3][d];
    if (t < DHD) {
        coff[((size_t)bh * 17 + c) * DHD + t] = off;
        if (c == NCC - 1) coff[((size_t)bh * 17 + 16) * DHD + t] = off + tot;
    }

    float run = 0.f;
    for (int ww = 0; ww < 4; ++ww) if (ww < w) run += part[ww][d];

    const size_t hbase = ((size_t)bh * LL + c * QQ + w * 16) * DHD + d;
    #pragma unroll
    for (int i = 0; i < 16; ++i) {
        const size_t gi = gbase + (size_t)i * DD;
        const float cv = Cf[gi];
        const float bv = Bf[gi];
        qf[hbase + (size_t)i * DHD] = cv * __expf(run);       // exp(Sm1 - Eprev)
        run += lar[i];
        const int rloc = w * 16 + i;
        smC[d][rloc] = run;       // Sloc
        smA[d][rloc] = cv;        // C
        smB[d][rloc] = bv;        // B
        kf[hbase + (size_t)i * DHD] = bv * __expf(tot - run); // exp(E - S)
    }
    __syncthreads();

    // ---- diag tile compute ----
    const int q0 = ((t >> 4) & 15) << 2;
    const int k0 = (t & 15) << 2;

    float acc[4][4] = {};
    if (q0 + 3 >= k0) {
        #pragma unroll 2
        for (int dd = 0; dd < DHD; ++dd) {
            const float4 cq = *(const float4*)&smA[dd][q0];
            const float4 bk = *(const float4*)&smB[dd][k0];
            const float4 sk = *(const float4*)&smC[dd][k0];
            const float cqa[4] = {cq.x, cq.y, cq.z, cq.w};
            const float bka[4] = {bk.x, bk.y, bk.z, bk.w};
            const float ska[4] = {sk.x, sk.y, sk.z, sk.w};
            float s1a[4];
            #pragma unroll
            for (int i = 0; i < 4; ++i) {
                const int qi = q0 + i;
                s1a[i] = (qi == 0) ? 0.f : smC[dd][qi - 1];
            }
            #pragma unroll
            for (int i = 0; i < 4; ++i) {
                #pragma unroll
                for (int j = 0; j < 4; ++j) {
                    const int qi = q0 + i, kj = k0 + j;
                    const float wgt = (qi > kj) ? __expf(s1a[i] - ska[j])
                                                : ((qi == kj) ? 1.f : 0.f);
                    acc[i][j] += cqa[i] * wgt * bka[j];
                }
            }
        }
    }
    const size_t outrow0 = ((size_t)bh * LL + (size_t)c * QQ) * LL + (size_t)c * QQ;
    #pragma unroll
    for (int i = 0; i < 4; ++i)
        *(float4*)&out[outrow0 + (size_t)(q0 + i) * LL + k0] =
            make_float4(acc[i][0], acc[i][1], acc[i][2], acc[i][3]);
}

// ---------------------------------------------------------------------------
// Kernel 3: band v5 = R8 structure + T14 async-stage split:
//  LOAD_K (global->reg, issued BEFORE MFMA) / WRITE_K (exp+split+ds_write,
//  AFTER MFMA+stores) so kf load latency hides under compute.
//  Block = (bh, m, half); n in [8*half, 8*half+8). One barrier per tile.
// ---------------------------------------------------------------------------
__global__ __launch_bounds__(256) void band_row(
    const float* __restrict__ qf, const float* __restrict__ kf,
    const float* __restrict__ coff, float* __restrict__ out)
{
    __shared__ unsigned char lds[49152];
    unsigned char* const l_qh = lds;
    unsigned char* const l_ql = lds + 8192;
    // k buffers: base 16384 + buf*16384, kh at +0, kl at +8192

    const int half = blockIdx.x & 1;
    const int m    = (blockIdx.x >> 1) & 15;
    const int bh   = blockIdx.x >> 5;
    const int n0   = half << 3;

    const int t  = threadIdx.x;
    const int wv = t >> 6;
    const int ln = t & 63;
    const int l15 = ln & 15;
    const int l4  = ln >> 4;
    const int wr = (wv >> 1) << 5;           // k-side half (A operand)
    const int wc = (wv & 1) << 5;            // q-side half (B operand)

    const int srow = t >> 2;                 // 0..63
    const int skc  = (t & 3) << 4;           // 0/16/32/48
    const int slot0 = skc >> 3;

    const size_t cb = (size_t)bh * 17 * DHD;
    const size_t outbase = ((size_t)bh * LL + (size_t)m * QQ) * LL;

    // ---- zero tiles (n > m within range) ----
    for (int n = (m >= n0 ? m + 1 : n0); n < n0 + 8; ++n) {
        const size_t ob = outbase + (size_t)srow * LL + (size_t)n * QQ + skc;
        const float4 z = make_float4(0.f, 0.f, 0.f, 0.f);
        *(float4*)&out[ob + 0]  = z;
        *(float4*)&out[ob + 4]  = z;
        *(float4*)&out[ob + 8]  = z;
        *(float4*)&out[ob + 12] = z;
    }

    const int ne = (m < n0 + 8) ? m : (n0 + 8);   // offdiag n in [n0, ne)
    if (n0 >= ne) return;

    // ---- coff[m] slice ----
    float cm[16];
    #pragma unroll
    for (int g = 0; g < 4; ++g) {
        const float4 a = *(const float4*)&coff[cb + (size_t)m * DHD + skc + g * 4];
        cm[g*4+0]=a.x; cm[g*4+1]=a.y; cm[g*4+2]=a.z; cm[g*4+3]=a.w;
    }

    // ---- stage qf_m once (hi/lo split) ----
    {
        const size_t qb = ((size_t)bh * LL + (size_t)m * QQ + srow) * DHD + skc;
        float v[16];
        #pragma unroll
        for (int g = 0; g < 4; ++g) {
            const float4 x4 = *(const float4*)&qf[qb + g * 4];
            v[g*4+0]=x4.x; v[g*4+1]=x4.y; v[g*4+2]=x4.z; v[g*4+3]=x4.w;
        }
        unsigned short h[16], l[16];
        #pragma unroll
        for (int i = 0; i < 16; ++i) bf16split(v[i], h[i], l[i]);
        *(uint4*)(l_qh + slot0*1024 + srow*16) =
            make_uint4(pk2(h[0],h[1]), pk2(h[2],h[3]), pk2(h[4],h[5]), pk2(h[6],h[7]));
        *(uint4*)(l_qh + (slot0+1)*1024 + srow*16) =
            make_uint4(pk2(h[8],h[9]), pk2(h[10],h[11]), pk2(h[12],h[13]), pk2(h[14],h[15]));
        *(uint4*)(l_ql + slot0*1024 + srow*16) =
            make_uint4(pk2(l[0],l[1]), pk2(l[2],l[3]), pk2(l[4],l[5]), pk2(l[6],l[7]));
        *(uint4*)(l_ql + (slot0+1)*1024 + srow*16) =
            make_uint4(pk2(l[8],l[9]), pk2(l[10],l[11]), pk2(l[12],l[13]), pk2(l[14],l[15]));
    }

    // ---- T14 split staging: LOAD (global->reg) / WRITE (exp+split+LDS) ----
    auto LOAD_K = [&](int n, float* vk, float* vc) {
        const size_t kb = ((size_t)bh * LL + (size_t)n * QQ + srow) * DHD + skc;
        #pragma unroll
        for (int g = 0; g < 4; ++g) {
            const float4 x4 = *(const float4*)&kf[kb + g * 4];
            vk[g*4+0]=x4.x; vk[g*4+1]=x4.y; vk[g*4+2]=x4.z; vk[g*4+3]=x4.w;
            const float4 c4 = *(const float4*)&coff[cb + (size_t)(n + 1) * DHD + skc + g * 4];
            vc[g*4+0]=c4.x; vc[g*4+1]=c4.y; vc[g*4+2]=c4.z; vc[g*4+3]=c4.w;
        }
    };

    auto WRITE_K = [&](int buf, const float* vk, const float* vc) {
        unsigned char* const kh_b = lds + 16384 + buf * 16384;
        unsigned char* const kl_b = kh_b + 8192;
        float v[16];
        #pragma unroll
        for (int i = 0; i < 16; ++i)
            v[i] = vk[i] * __expf(cm[i] - vc[i]);
        unsigned short h[16], l[16];
        #pragma unroll
        for (int i = 0; i < 16; ++i) bf16split(v[i], h[i], l[i]);
        *(uint4*)(kh_b + slot0*1024 + srow*16) =
            make_uint4(pk2(h[0],h[1]), pk2(h[2],h[3]), pk2(h[4],h[5]), pk2(h[6],h[7]));
        *(uint4*)(kh_b + (slot0+1)*1024 + srow*16) =
            make_uint4(pk2(h[8],h[9]), pk2(h[10],h[11]), pk2(h[12],h[13]), pk2(h[14],h[15]));
        *(uint4*)(kl_b + slot0*1024 + srow*16) =
            make_uint4(pk2(l[0],l[1]), pk2(l[2],l[3]), pk2(l[4],l[5]), pk2(l[6],l[7]));
        *(uint4*)(kl_b + (slot0+1)*1024 + srow*16) =
            make_uint4(pk2(l[8],l[9]), pk2(l[10],l[11]), pk2(l[12],l[13]), pk2(l[14],l[15]));
    };

    {
        float pk0[16], pc0[16];
        LOAD_K(n0, pk0, pc0);
        WRITE_K(0, pk0, pc0);
    }
    __syncthreads();

    int cur = 0;
    for (int n = n0; n < ne; ++n) {
        float nk[16], nc[16];
        const bool pre = (n + 1 < ne);
        if (pre) LOAD_K(n + 1, nk, nc);          // loads issue; no use yet

        const unsigned char* const kh_b = lds + 16384 + cur * 16384;
        const unsigned char* const kl_b = kh_b + 8192;

        f4 acc[2][2] = {};   // MFMA overlaps the in-flight loads
        #pragma unroll
        for (int ks = 0; ks < 2; ++ks) {
            const int ka = (ks * 4 + l4) * 1024;
            const s8b kh0 = *(const s8b*)(kh_b + ka + (wr      + l15) * 16);
            const s8b kh1 = *(const s8b*)(kh_b + ka + (wr + 16 + l15) * 16);
            const s8b kl0 = *(const s8b*)(kl_b + ka + (wr      + l15) * 16);
            const s8b kl1 = *(const s8b*)(kl_b + ka + (wr + 16 + l15) * 16);
            const s8b qh0 = *(const s8b*)(l_qh + ka + (wc      + l15) * 16);
            const s8b qh1 = *(const s8b*)(l_qh + ka + (wc + 16 + l15) * 16);
            const s8b ql0 = *(const s8b*)(l_ql + ka + (wc      + l15) * 16);
            const s8b ql1 = *(const s8b*)(l_ql + ka + (wc + 16 + l15) * 16);

            acc[0][0] = __builtin_amdgcn_mfma_f32_16x16x32_bf16(kh0, qh0, acc[0][0], 0, 0, 0);
            acc[0][1] = __builtin_amdgcn_mfma_f32_16x16x32_bf16(kh0, qh1, acc[0][1], 0, 0, 0);
            acc[1][0] = __builtin_amdgcn_mfma_f32_16x16x32_bf16(kh1, qh0, acc[1][0], 0, 0, 0);
            acc[1][1] = __builtin_amdgcn_mfma_f32_16x16x32_bf16(kh1, qh1, acc[1][1], 0, 0, 0);
            acc[0][0] = __builtin_amdgcn_mfma_f32_16x16x32_bf16(kh0, ql0, acc[0][0], 0, 0, 0);
            acc[0][1] = __builtin_amdgcn_mfma_f32_16x16x32_bf16(kh0, ql1, acc[0][1], 0, 0, 0);
            acc[1][0] = __builtin_amdgcn_mfma_f32_16x16x32_bf16(kh1, ql0, acc[1][0], 0, 0, 0);
            acc[1][1] = __builtin_amdgcn_mfma_f32_16x16x32_bf16(kh1, ql1, acc[1][1], 0, 0, 0);
            acc[0][0] = __builtin_amdgcn_mfma_f32_16x16x32_bf16(kl0, qh0, acc[0][0], 0, 0, 0);
            acc[0][1] = __builtin_amdgcn_mfma_f32_16x16x32_bf16(kl0, qh1, acc[0][1], 0, 0, 0);
            acc[1][0] = __builtin_amdgcn_mfma_f32_16x16x32_bf16(kl1, qh0, acc[1][0], 0, 0, 0);
            acc[1][1] = __builtin_amdgcn_mfma_f32_16x16x32_bf16(kl1, qh1, acc[1][1], 0, 0, 0);
        }

        // stores in flight before the dependent exp/split of the prefetch
        #pragma unroll
        for (int ms = 0; ms < 2; ++ms) {
            #pragma unroll
            for (int ns = 0; ns < 2; ++ns) {
                const int q  = wc + ns * 16 + l15;
                const int k0 = wr + ms * 16 + l4 * 4;
                *(float4*)&out[outbase + (size_t)q * LL + (size_t)n * QQ + k0] =
                    make_float4(acc[ms][ns][0], acc[ms][ns][1], acc[ms][ns][2], acc[ms][ns][3]);
            }
        }

        if (pre) WRITE_K(cur ^ 1, nk, nc);       // vmcnt waits land here

        __syncthreads();   // staged n+1 visible; buf cur free for overwrite
        cur ^= 1;
    }
}

// ---------------------------------------------------------------------------
extern "C" void kernel_launch(void* const* d_in, const int* in_sizes, int n_in,
                              void* d_out, int out_size, void* d_ws, size_t ws_size,
                              hipStream_t stream) {
    const float* x  = (const float*)d_in[0];
    const float* Wa = (const float*)d_in[1];
    const float* ba = (const float*)d_in[2];
    const float* Wb = (const float*)d_in[3];
    const float* bb = (const float*)d_in[4];
    const float* Wc = (const float*)d_in[5];
    const float* bc = (const float*)d_in[6];
    float* out = (float*)d_out;
    float* ws  = (float*)d_ws;

    const size_t NBLD = (size_t)BB * LL * DD;   // 1,048,576 floats
    float* logA = ws;
    float* Bf   = ws + 1 * NBLD;
    float* Cf   = ws + 2 * NBLD;
    // slot 3 holds the bf16 split staging arrays
    float* qf   = ws + 4 * NBLD;
    float* kf   = ws + 5 * NBLD;
    float* coff = ws + 6 * NBLD;                        // 16*17*64 floats
    float* csum = coff + (size_t)BB * HH * 17 * DHD;    // 256*64 floats

    unsigned short* xh  = (unsigned short*)(ws + 3 * NBLD);
    unsigned short* xl  = xh + 1048576;
    unsigned short* whp = xl + 1048576;    // 3 x 262144 (overlaps qf region,
    unsigned short* wlp = whp + 786432;    //  consumed before scan writes qf)

    convert_split<<<1792, 256, 0, stream>>>(x, Wa, Wb, Wc, xh, xl, whp, wlp);
    gemm3_fused<<<256, 512, 0, stream>>>(xh, xl, whp, wlp, ba, bb, bc, logA, Bf, Cf, csum);
    scan_diag<<<BB * HH * NCC, 256, 0, stream>>>(logA, Bf, Cf, csum, qf, kf, coff, out);
    band_row<<<BB * HH * NCC * 2, 256, 0, stream>>>(qf, kf, coff, out);
}